// Round 1
// 1543.316 us; speedup vs baseline: 1.1331x; 1.1331x over previous
//
#include <hip/hip_runtime.h>
#include <cstdint>
#include <cstddef>

#define T_DIM 8
#define V_DIM 10000
#define E_DIM 100000
#define VS (V_DIM * 256)

typedef __attribute__((ext_vector_type(8))) short short8;
typedef __attribute__((ext_vector_type(4))) float floatx4;

__device__ __forceinline__ unsigned int f2bf(float f) {
    union { float f; unsigned int u; } v; v.f = f;
    unsigned int u = v.u;
    u = u + 0x7FFFu + ((u >> 16) & 1u);   // RNE
    return u >> 16;
}
__device__ __forceinline__ float bf2f(unsigned int s) {
    union { unsigned int u; float f; } v; v.u = s << 16;
    return v.f;
}
__device__ __forceinline__ short8 relu8(short8 x) {
    const short8 z = {0,0,0,0,0,0,0,0};
    return __builtin_elementwise_max(x, z);   // v_pk_max_i16: bf16 relu on bit pattern
}
union PK { uint4 u; short8 s; };

// ---- pack fp32 weight [K,Nw] into MFMA B-fragment order inside a concat buffer
__global__ void pack_b_kernel(const float* __restrict__ w, unsigned short* __restrict__ out,
                              int K, int Nw, int NTN_tot, int nt_off) {
    int tid = blockIdx.x * blockDim.x + threadIdx.x;
    int total = (K >> 5) * (Nw >> 4) * 64;
    if (tid >= total) return;
    int lane = tid & 63;
    int f = tid >> 6;
    int ntn_w = Nw >> 4;
    int nt = f % ntn_w;
    int kt = f / ntn_w;
    int kbase = kt * 32 + ((lane >> 4) << 3);
    int n = nt * 16 + (lane & 15);
    unsigned int vals[8];
#pragma unroll
    for (int j = 0; j < 8; ++j)
        vals[j] = f2bf(w[(size_t)(kbase + j) * Nw + n]);
    uint4 pk;
    pk.x = vals[0] | (vals[1] << 16);
    pk.y = vals[2] | (vals[3] << 16);
    pk.z = vals[4] | (vals[5] << 16);
    pk.w = vals[6] | (vals[7] << 16);
    size_t fo = (size_t)kt * NTN_tot + nt_off + nt;
    *(uint4*)(out + (fo * 64 + lane) * 8) = pk;
}

// ---- token mixer ----
__global__ void token_mix_kernel(const float* __restrict__ xs, const float* __restrict__ w_pre,
                                 const float* __restrict__ b_pre, unsigned short* __restrict__ ob) {
    const int S = V_DIM * 128;
    int tid = blockIdx.x * blockDim.x + threadIdx.x;
    if (tid >= T_DIM * S / 4) return;
    int e = tid * 4;
    int t = e / S;
    int c = e & 127;
    floatx4 xm = {0.f,0.f,0.f,0.f}, xp = {0.f,0.f,0.f,0.f};
    floatx4 x0 = *(const floatx4*)(xs + e);
    if (t > 0)          xm = *(const floatx4*)(xs + e - S);
    if (t < T_DIM - 1)  xp = *(const floatx4*)(xs + e + S);
    uint2 p; unsigned int b[4];
#pragma unroll
    for (int j = 0; j < 4; ++j) {
        int cc = c + j;
        float r = xm[j]*w_pre[cc*3+0] + x0[j]*w_pre[cc*3+1] + xp[j]*w_pre[cc*3+2] + b_pre[cc];
        b[j] = f2bf(r);
    }
    p.x = b[0] | (b[1] << 16);
    p.y = b[2] | (b[3] << 16);
    *(uint2*)(ob + e) = p;
}

// ---- P0[d][k] = B0[k]*lam0^d ; P1[d][k] = B1[k]*lam1^d  (d = 0..7) ----
__global__ void lamP_kernel(const float* __restrict__ a0, const float* __restrict__ a1,
                            const float* __restrict__ B0, const float* __restrict__ B1,
                            float* __restrict__ P0, float* __restrict__ P1) {
    int i = blockIdx.x * blockDim.x + threadIdx.x;
    if (i >= 4096) return;
    float l0 = expf(-expf(a0[i]));
    float l1 = expf(-expf(a1[i]));
    float p0 = B0[i], p1 = B1[i];
#pragma unroll
    for (int d = 0; d < 8; ++d) {
        P0[d * 4096 + i] = p0;
        P1[d * 4096 + i] = p1;
        p0 *= l0; p1 *= l1;
    }
}

// ---- bias concat: [b_sage | 0 | b_res] per layer (region order self|neigh|res) ----
__global__ void bias_cat_kernel(const float* __restrict__ br0, const float* __restrict__ bs0,
                                const float* __restrict__ br1, const float* __restrict__ bs1,
                                float* __restrict__ bcat0, float* __restrict__ bcat1) {
    int i = blockIdx.x * blockDim.x + threadIdx.x;
    if (i >= 768) return;
    bcat0[i] = (i < 256) ? bs0[i] : (i < 512 ? 0.f : br0[i - 512]);
    bcat1[i] = (i < 256) ? bs1[i] : (i < 512 ? 0.f : br1[i - 512]);
}

// ================= CSR build =================
__global__ void deg_kernel(const int* __restrict__ ei, int* __restrict__ deg_cnt) {
    int tid = blockIdx.x * blockDim.x + threadIdx.x;
    if (tid >= T_DIM * E_DIM) return;
    int t = tid / E_DIM;
    int e = tid - t * E_DIM;
    int dst = ei[(size_t)t * 2 * E_DIM + E_DIM + e];
    if ((unsigned)dst < V_DIM) atomicAdd(deg_cnt + t * V_DIM + dst, 1);
}

__global__ void invdeg_kernel(const int* __restrict__ deg_cnt, float* __restrict__ inv) {
    int tid = blockIdx.x * blockDim.x + threadIdx.x;
    if (tid >= T_DIM * V_DIM) return;
    inv[tid] = 1.0f / (float)max(deg_cnt[tid], 1);
}

__global__ __launch_bounds__(1024)
void scan_kernel(const int* __restrict__ deg_cnt, int* __restrict__ rowptr) {
    __shared__ int sums[1024];
    int t = blockIdx.x;
    const int* d = deg_cnt + t * V_DIM;
    int* rp = rowptr + t * (V_DIM + 1);
    int tid = threadIdx.x;
    int base = tid * 10;
    int loc[10]; int s = 0;
#pragma unroll
    for (int j = 0; j < 10; ++j) {
        int v = base + j;
        int x = (v < V_DIM) ? d[v] : 0;
        loc[j] = s; s += x;
    }
    sums[tid] = s;
    __syncthreads();
    for (int o = 1; o < 1024; o <<= 1) {
        int v = (tid >= o) ? sums[tid - o] : 0;
        __syncthreads();
        sums[tid] += v;
        __syncthreads();
    }
    int prev = (tid == 0) ? 0 : sums[tid - 1];
#pragma unroll
    for (int j = 0; j < 10; ++j) {
        int v = base + j;
        if (v < V_DIM) rp[v] = prev + loc[j];
    }
    if (tid == 1023) rp[V_DIM] = sums[1023];
}

__global__ void fill_kernel(const int* __restrict__ ei, const int* __restrict__ rowptr,
                            int* __restrict__ fill_cnt, int* __restrict__ srcs) {
    int tid = blockIdx.x * blockDim.x + threadIdx.x;
    if (tid >= T_DIM * E_DIM) return;
    int t = tid / E_DIM;
    int e = tid - t * E_DIM;
    const int* eit = ei + (size_t)t * 2 * E_DIM;
    int src = eit[e];
    int dst = eit[E_DIM + e];
    if ((unsigned)src >= V_DIM || (unsigned)dst >= V_DIM) return;
    int pos = rowptr[t * (V_DIM + 1) + dst] + atomicAdd(fill_cnt + t * V_DIM + dst, 1);
    srcs[(size_t)t * E_DIM + pos] = src;
}

// ---- gather + slot-pack: h = hb + (sum xn[src])*invdeg, written to hpack[v][c][slot]
__global__ void gather_pack_kernel(const unsigned short* __restrict__ xn, const int* __restrict__ srcs,
                                   const int* __restrict__ rowptr, const float* __restrict__ invdeg,
                                   const unsigned short* __restrict__ hb,
                                   unsigned short* __restrict__ hpack, int slot) {
    int gw = (blockIdx.x * blockDim.x + threadIdx.x) >> 6;
    int lane = threadIdx.x & 63;
    if (gw >= V_DIM) return;
    int beg = rowptr[gw], end = rowptr[gw + 1];
    float a0 = 0.f, a1 = 0.f, a2 = 0.f, a3 = 0.f;
    for (int i = beg; i < end; ++i) {
        int s = srcs[i];
        uint2 p = *(const uint2*)(xn + (size_t)s * 256 + lane * 4);
        a0 += bf2f(p.x & 0xffffu);
        a1 += bf2f(p.x >> 16);
        a2 += bf2f(p.y & 0xffffu);
        a3 += bf2f(p.y >> 16);
    }
    float inv = invdeg[gw];
    uint2 h = *(const uint2*)(hb + (size_t)gw * 256 + lane * 4);
    a0 = a0 * inv + bf2f(h.x & 0xffffu);
    a1 = a1 * inv + bf2f(h.x >> 16);
    a2 = a2 * inv + bf2f(h.y & 0xffffu);
    a3 = a3 * inv + bf2f(h.y >> 16);
    unsigned short* op = hpack + (size_t)gw * 2048 + (size_t)(lane * 4) * 8 + slot;
    op[0]  = (unsigned short)f2bf(a0);
    op[8]  = (unsigned short)f2bf(a1);
    op[16] = (unsigned short)f2bf(a2);
    op[24] = (unsigned short)f2bf(a3);
}

// ---- cat GEMM: x(t) @ [w_self|w_neigh|w_res]; region 0->bf16 d_self, 1->bf16 d_xn, 2->f32 d_xsr
template<int KT>
__global__ __launch_bounds__(256, 4)
void gemm_cat3_kernel(const unsigned short* __restrict__ A, const unsigned short* __restrict__ Bp,
                      const float* __restrict__ bias, unsigned short* __restrict__ d_self,
                      unsigned short* __restrict__ d_xn, float* __restrict__ d_xsr, int M) {
    const int w = threadIdx.x >> 6, lane = threadIdx.x & 63;
    const int quad = lane >> 4, l16 = lane & 15;
    const int region = blockIdx.x;
    const int m0 = blockIdx.y * 64;
    constexpr int K = KT * 32;
    floatx4 acc[4][4];
#pragma unroll
    for (int a = 0; a < 4; ++a)
#pragma unroll
        for (int b = 0; b < 4; ++b) acc[a][b] = (floatx4){0.f,0.f,0.f,0.f};
    const unsigned short* arow[4];
#pragma unroll
    for (int mi = 0; mi < 4; ++mi) {
        int r = m0 + mi * 16 + l16;
        if (r > M - 1) r = M - 1;
        arow[mi] = A + (size_t)r * K + quad * 8;
    }
    const unsigned short* bptr = Bp + ((size_t)(region * 16 + w * 4) * 64 + lane) * 8;
#pragma unroll
    for (int kt = 0; kt < KT; ++kt) {
        short8 bfr[4];
#pragma unroll
        for (int i = 0; i < 4; ++i) bfr[i] = *(const short8*)(bptr + i * 512);
        short8 af[4];
#pragma unroll
        for (int mi = 0; mi < 4; ++mi) af[mi] = *(const short8*)(arow[mi]);
#pragma unroll
        for (int mi = 0; mi < 4; ++mi)
#pragma unroll
            for (int i = 0; i < 4; ++i)
                acc[mi][i] = __builtin_amdgcn_mfma_f32_16x16x32_bf16(af[mi], bfr[i], acc[mi][i], 0, 0, 0);
        bptr += 48 * 512;
#pragma unroll
        for (int mi = 0; mi < 4; ++mi) arow[mi] += 32;
    }
#pragma unroll
    for (int mi = 0; mi < 4; ++mi) {
        int rbase = m0 + mi * 16 + quad * 4;
#pragma unroll
        for (int i = 0; i < 4; ++i) {
            int lcol = w * 64 + i * 16 + l16;
            float b = bias[region * 256 + lcol];
#pragma unroll
            for (int rr = 0; rr < 4; ++rr) {
                int row = rbase + rr;
                if (row < M) {
                    float v = acc[mi][i][rr] + b;
                    size_t off = (size_t)row * 256 + lcol;
                    if (region == 0) d_self[off] = (unsigned short)f2bf(v);
                    else if (region == 1) d_xn[off] = (unsigned short)f2bf(v);
                    else d_xsr[off] = v;
                }
            }
        }
    }
}

// ---- fused closed-form SSM + split-K(4) mix GEMM, cooperative A-fragment build ----
// Each block: 64 rows x 256 cols, K-slice = 1024 (= 4 phases of 8 kt).
// Phase 1: 256 threads compute each state EXACTLY ONCE (no 4x wave redundancy),
//          relu+pack to bf16 MFMA A-fragments in LDS. P held in registers (L2-hot).
// Phase 2: MFMA loop reads A-fragments from LDS (contiguous ds_read_b128).
template<int TT>
__global__ __launch_bounds__(256, 3)
void gemm_mix_cf4_kernel(const unsigned short* __restrict__ hp,   // [V][256][8]
                         const unsigned short* __restrict__ Bp,   // packed w_mix
                         const float* __restrict__ P,             // [8][4096]
                         float* __restrict__ part, int M) {
    __shared__ unsigned short Afrag[8 * 4 * 64 * 8];   // 32 KiB: [kt][mi][lane][8]
    const int tid = threadIdx.x;
    const int w = tid >> 6, lane = tid & 63;
    const int quad = lane >> 4, l16 = lane & 15;
    const int ks = blockIdx.x;           // 0..3  (K slice of 1024)
    const int m0 = blockIdx.y * 64;
    // phase-1 work assignment: thread -> (kt1, kq, rsel); 8 rows x 8 k each
    const int kt1 = tid >> 5;            // 0..7  kt within phase
    const int kq  = (tid >> 3) & 3;      // 0..3  k-quad (8 k)
    const int rsel= tid & 7;             // 0..7  row class (stride 8)

    floatx4 acc[4][4];
#pragma unroll
    for (int a = 0; a < 4; ++a)
#pragma unroll
        for (int b = 0; b < 4; ++b) acc[a][b] = (floatx4){0.f,0.f,0.f,0.f};

    const unsigned short* bptr = Bp + ((size_t)(ks * 512 + w * 4) * 64 + lane) * 8;

    for (int p = 0; p < 4; ++p) {
        // ---- phase 1: cooperative state compute -> Afrag ----
        const int kg = ks * 1024 + p * 256 + kt1 * 32 + kq * 8;   // global k base
        const int hh = kg >> 4;                                    // h channel
        floatx4 p0r[TT + 1], p1r[TT + 1];
#pragma unroll
        for (int tau = 0; tau <= TT; ++tau) {
            const float* Pd = P + (size_t)(TT - tau) * 4096 + kg;
            p0r[tau] = *(const floatx4*)Pd;
            p1r[tau] = *(const floatx4*)(Pd + 4);
        }
        const int abase = kt1 * 256 + kq * 16;
        for (int g = 0; g < 8; ++g) {
            int r = rsel + g * 8;                 // block-local row 0..63
            int rg = m0 + r; if (rg > M - 1) rg = M - 1;
            PK h8; h8.u = *(const uint4*)(hp + (size_t)rg * 2048 + hh * 8);
            float sv[8];
#pragma unroll
            for (int j = 0; j < 8; ++j) sv[j] = 0.f;
#pragma unroll
            for (int tau = 0; tau <= TT; ++tau) {
                float hv = bf2f((unsigned int)(unsigned short)h8.s[tau]);
#pragma unroll
                for (int j = 0; j < 4; ++j) {
                    sv[j]     += hv * p0r[tau][j];
                    sv[4 + j] += hv * p1r[tau][j];
                }
            }
            PK cv;
            cv.u.x = f2bf(sv[0]) | (f2bf(sv[1]) << 16);
            cv.u.y = f2bf(sv[2]) | (f2bf(sv[3]) << 16);
            cv.u.z = f2bf(sv[4]) | (f2bf(sv[5]) << 16);
            cv.u.w = f2bf(sv[6]) | (f2bf(sv[7]) << 16);
            PK st; st.s = relu8(cv.s);
            int mi = r >> 4, rl = r & 15;
            *(uint4*)(Afrag + (size_t)(abase + mi * 64 + rl) * 8) = st.u;
        }
        __syncthreads();
        // ---- phase 2: MFMA over this phase's 8 kt ----
#pragma unroll
        for (int kt = 0; kt < 8; ++kt) {
            short8 bfr[4];
#pragma unroll
            for (int i = 0; i < 4; ++i) bfr[i] = *(const short8*)(bptr + i * 512);
            short8 af[4];
#pragma unroll
            for (int mi = 0; mi < 4; ++mi)
                af[mi] = *(const short8*)(Afrag + (size_t)((kt * 4 + mi) * 64 + lane) * 8);
#pragma unroll
            for (int mi = 0; mi < 4; ++mi)
#pragma unroll
                for (int i = 0; i < 4; ++i)
                    acc[mi][i] = __builtin_amdgcn_mfma_f32_16x16x32_bf16(af[mi], bfr[i], acc[mi][i], 0, 0, 0);
            bptr += 16 * 512;
        }
        __syncthreads();
    }
#pragma unroll
    for (int mi = 0; mi < 4; ++mi) {
        int rbase = m0 + mi * 16 + quad * 4;
#pragma unroll
        for (int i = 0; i < 4; ++i) {
            int col = w * 64 + i * 16 + l16;
#pragma unroll
            for (int rr = 0; rr < 4; ++rr) {
                int row = rbase + rr;
                if (row < M)
                    part[((size_t)ks * M + row) * 256 + col] = acc[mi][i][rr];
            }
        }
    }
}

// ---- reduce NS split-K partials + bias + resid -> bf16 ----
template<int NS>
__global__ void reduceN_kernel(const float* __restrict__ part, const float* __restrict__ bias,
                               const float* __restrict__ resid, unsigned short* __restrict__ out, int M) {
    int tid = blockIdx.x * blockDim.x + threadIdx.x;
    if (tid >= M * 64) return;
    size_t i4 = (size_t)tid * 4;
    const size_t S = (size_t)M * 256;
    floatx4 rv = *(const floatx4*)(resid + i4);
    floatx4 bv = *(const floatx4*)(bias + (i4 & 255));
    float v0 = rv[0] + bv[0], v1 = rv[1] + bv[1], v2 = rv[2] + bv[2], v3 = rv[3] + bv[3];
#pragma unroll
    for (int s = 0; s < NS; ++s) {
        floatx4 p = *(const floatx4*)(part + (size_t)s * S + i4);
        v0 += p[0]; v1 += p[1]; v2 += p[2]; v3 += p[3];
    }
    uint2 o;
    o.x = f2bf(v0) | (f2bf(v1) << 16);
    o.y = f2bf(v2) | (f2bf(v3) << 16);
    *(uint2*)(out + i4) = o;
}

// ---- small GEMM (head): 32-row blocks, 8 waves ----
template<int NT, int NTN_TOT, bool RELU>
__global__ __launch_bounds__(512)
void gemm16_kernel(const unsigned short* __restrict__ A, const unsigned short* __restrict__ Bp,
                   const float* __restrict__ bias, float* __restrict__ outF, int M, int K) {
    const int w = threadIdx.x >> 6, lane = threadIdx.x & 63;
    const int quad = lane >> 4, l16 = lane & 15;
    const int rowgrp = w >> 2, nchunk = w & 3;
    const int m0 = blockIdx.x * 32 + rowgrp * 16;
    const int ntb = nchunk * NT;
    constexpr int Ntot = NTN_TOT * 16;
    floatx4 acc[NT];
#pragma unroll
    for (int i = 0; i < NT; ++i) acc[i] = (floatx4){0.f,0.f,0.f,0.f};
    int r = m0 + l16; if (r > M - 1) r = M - 1;
    const unsigned short* arow = A + (size_t)r * K + quad * 8;
    const int ksteps = K >> 5;
    for (int kt = 0; kt < ksteps; ++kt) {
        short8 af = *(const short8*)(arow + kt * 32);
        if (RELU) af = relu8(af);
#pragma unroll
        for (int i = 0; i < NT; ++i) {
            short8 bf = *(const short8*)(Bp + ((size_t)(kt * NTN_TOT + ntb + i) * 64 + lane) * 8);
            acc[i] = __builtin_amdgcn_mfma_f32_16x16x32_bf16(af, bf, acc[i], 0, 0, 0);
        }
    }
    const int rbase = m0 + quad * 4;
#pragma unroll
    for (int i = 0; i < NT; ++i) {
        int col = (ntb + i) * 16 + l16;
        float b = bias[col];
#pragma unroll
        for (int rr = 0; rr < 4; ++rr) {
            int row = rbase + rr;
            if (row < M)
                outF[(size_t)row * Ntot + col] = acc[i][rr] + b;
        }
    }
}

extern "C" void kernel_launch(void* const* d_in, const int* in_sizes, int n_in,
                              void* d_out, int out_size, void* d_ws, size_t ws_size,
                              hipStream_t stream) {
    const float* xs      = (const float*)d_in[0];
    const int*   ei      = (const int*)d_in[1];
    const float* w_pre   = (const float*)d_in[2];
    const float* b_pre   = (const float*)d_in[3];
    const float* w_res0  = (const float*)d_in[4];
    const float* b_res0  = (const float*)d_in[5];
    const float* w_self0 = (const float*)d_in[6];
    const float* w_neigh0= (const float*)d_in[7];
    const float* b_sage0 = (const float*)d_in[8];
    const float* a_log0  = (const float*)d_in[9];
    const float* B0      = (const float*)d_in[10];
    const float* w_mix0  = (const float*)d_in[11];
    const float* b_mix0  = (const float*)d_in[12];
    const float* w_res1  = (const float*)d_in[13];
    const float* b_res1  = (const float*)d_in[14];
    const float* w_self1 = (const float*)d_in[15];
    const float* w_neigh1= (const float*)d_in[16];
    const float* b_sage1 = (const float*)d_in[17];
    const float* a_log1  = (const float*)d_in[18];
    const float* B1      = (const float*)d_in[19];
    const float* w_mix1  = (const float*)d_in[20];
    const float* b_mix1  = (const float*)d_in[21];
    const float* w_out   = (const float*)d_in[22];
    const float* b_out   = (const float*)d_in[23];

    char* wsB = (char*)d_ws;
    size_t off = 0;
    auto alloc = [&](size_t bytes) {
        char* p = wsB + off;
        off += (bytes + 255) & ~(size_t)255;
        return p;
    };
    unsigned short* x0b   = (unsigned short*)alloc((size_t)T_DIM * V_DIM * 128 * 2);
    unsigned short* hpack0= (unsigned short*)alloc((size_t)V_DIM * 2048 * 2);   // [V][256][8] layer-0 h
    unsigned short* hpack1= (unsigned short*)alloc((size_t)V_DIM * 2048 * 2);   // [V][256][8] layer-1 h
    unsigned short* hb_t  = (unsigned short*)alloc((size_t)VS * 2);
    unsigned short* x1b_t = (unsigned short*)alloc((size_t)VS * 2);
    unsigned short* xn_t  = (unsigned short*)alloc((size_t)VS * 2);
    float*          xsr_t = (float*)alloc((size_t)VS * 4);
    float*          part  = (float*)alloc((size_t)4 * VS * 4);
    unsigned short* out1_b= (unsigned short*)alloc((size_t)VS * 2);
    int*            deg_cnt = (int*)alloc((size_t)T_DIM * V_DIM * 4);
    float*          invdeg  = (float*)alloc((size_t)T_DIM * V_DIM * 4);
    int*            rowptr  = (int*)alloc((size_t)T_DIM * (V_DIM + 1) * 4);
    int*            fill_cnt= (int*)alloc((size_t)T_DIM * V_DIM * 4);
    int*            srcs    = (int*)alloc((size_t)T_DIM * E_DIM * 4);
    float*          P0    = (float*)alloc(8 * 4096 * 4);
    float*          P1    = (float*)alloc(8 * 4096 * 4);
    float*          bcat0 = (float*)alloc(768 * 4);
    float*          bcat1 = (float*)alloc(768 * 4);
    unsigned short* wcat0p= (unsigned short*)alloc((size_t)128 * 768 * 2);
    unsigned short* wcat1p= (unsigned short*)alloc((size_t)256 * 768 * 2);
    unsigned short* wmix0p= (unsigned short*)alloc((size_t)4096 * 256 * 2);
    unsigned short* wmix1p= (unsigned short*)alloc((size_t)4096 * 256 * 2);
    unsigned short* woutp = (unsigned short*)alloc((size_t)256 * 64 * 2);
    if (off > ws_size) return;   // fail cleanly, not a GPU fault

    auto cdiv = [](int a, int b) { return (a + b - 1) / b; };
    const int gM64 = cdiv(V_DIM, 64);    // 157
    const int gGat = cdiv(V_DIM * 64, 256);
    const int gRed = cdiv(V_DIM * 64, 256);

    auto launch_mix = [&](int t, const unsigned short* hp, const unsigned short* wp,
                          const float* P) {
        dim3 g(4, gM64);
        switch (t) {
        case 0: gemm_mix_cf4_kernel<0><<<g, 256, 0, stream>>>(hp, wp, P, part, V_DIM); break;
        case 1: gemm_mix_cf4_kernel<1><<<g, 256, 0, stream>>>(hp, wp, P, part, V_DIM); break;
        case 2: gemm_mix_cf4_kernel<2><<<g, 256, 0, stream>>>(hp, wp, P, part, V_DIM); break;
        case 3: gemm_mix_cf4_kernel<3><<<g, 256, 0, stream>>>(hp, wp, P, part, V_DIM); break;
        case 4: gemm_mix_cf4_kernel<4><<<g, 256, 0, stream>>>(hp, wp, P, part, V_DIM); break;
        case 5: gemm_mix_cf4_kernel<5><<<g, 256, 0, stream>>>(hp, wp, P, part, V_DIM); break;
        case 6: gemm_mix_cf4_kernel<6><<<g, 256, 0, stream>>>(hp, wp, P, part, V_DIM); break;
        default: gemm_mix_cf4_kernel<7><<<g, 256, 0, stream>>>(hp, wp, P, part, V_DIM); break;
        }
    };

    // ---- parameter prep ----
    lamP_kernel<<<16, 256, 0, stream>>>(a_log0, a_log1, B0, B1, P0, P1);
    bias_cat_kernel<<<3, 256, 0, stream>>>(b_res0, b_sage0, b_res1, b_sage1, bcat0, bcat1);
    // region order: [self | neigh | res]
    pack_b_kernel<<<cdiv(4*16*64, 256), 256, 0, stream>>>(w_self0,  wcat0p, 128, 256, 48, 0);
    pack_b_kernel<<<cdiv(4*16*64, 256), 256, 0, stream>>>(w_neigh0, wcat0p, 128, 256, 48, 16);
    pack_b_kernel<<<cdiv(4*16*64, 256), 256, 0, stream>>>(w_res0,   wcat0p, 128, 256, 48, 32);
    pack_b_kernel<<<cdiv(8*16*64, 256), 256, 0, stream>>>(w_self1,  wcat1p, 256, 256, 48, 0);
    pack_b_kernel<<<cdiv(8*16*64, 256), 256, 0, stream>>>(w_neigh1, wcat1p, 256, 256, 48, 16);
    pack_b_kernel<<<cdiv(8*16*64, 256), 256, 0, stream>>>(w_res1,   wcat1p, 256, 256, 48, 32);
    pack_b_kernel<<<cdiv(128*16*64, 256), 256, 0, stream>>>(w_mix0, wmix0p, 4096, 256, 16, 0);
    pack_b_kernel<<<cdiv(128*16*64, 256), 256, 0, stream>>>(w_mix1, wmix1p, 4096, 256, 16, 0);
    pack_b_kernel<<<cdiv(8*4*64, 256), 256, 0, stream>>>(w_out, woutp, 256, 64, 4, 0);

    // ---- token mixer + CSR build ----
    token_mix_kernel<<<cdiv(T_DIM*V_DIM*128/4, 256), 256, 0, stream>>>(xs, w_pre, b_pre, x0b);
    hipMemsetAsync(deg_cnt, 0, (size_t)T_DIM * V_DIM * 4, stream);
    hipMemsetAsync(fill_cnt, 0, (size_t)T_DIM * V_DIM * 4, stream);
    deg_kernel<<<cdiv(T_DIM*E_DIM, 256), 256, 0, stream>>>(ei, deg_cnt);
    scan_kernel<<<T_DIM, 1024, 0, stream>>>(deg_cnt, rowptr);
    invdeg_kernel<<<cdiv(T_DIM*V_DIM, 256), 256, 0, stream>>>(deg_cnt, invdeg);
    fill_kernel<<<cdiv(T_DIM*E_DIM, 256), 256, 0, stream>>>(ei, rowptr, fill_cnt, srcs);

    // ================= main loop over t =================
    for (int t = 0; t < T_DIM; ++t) {
        // ---- layer 0 ----
        gemm_cat3_kernel<4><<<dim3(3, gM64), 256, 0, stream>>>(
            x0b + (size_t)t * V_DIM * 128, wcat0p, bcat0, hb_t, xn_t, xsr_t, V_DIM);
        gather_pack_kernel<<<gGat, 256, 0, stream>>>(
            xn_t, srcs + (size_t)t * E_DIM, rowptr + (size_t)t * (V_DIM + 1),
            invdeg + (size_t)t * V_DIM, hb_t, hpack0, t);
        launch_mix(t, hpack0, wmix0p, P0);
        reduceN_kernel<4><<<gRed, 256, 0, stream>>>(part, b_mix0, xsr_t, x1b_t, V_DIM);
        // ---- layer 1 (xsr region only needed at t=7) ----
        gemm_cat3_kernel<8><<<dim3(t == T_DIM - 1 ? 3 : 2, gM64), 256, 0, stream>>>(
            x1b_t, wcat1p, bcat1, hb_t, xn_t, xsr_t, V_DIM);
        gather_pack_kernel<<<gGat, 256, 0, stream>>>(
            xn_t, srcs + (size_t)t * E_DIM, rowptr + (size_t)t * (V_DIM + 1),
            invdeg + (size_t)t * V_DIM, hb_t, hpack1, t);
    }

    // ================= layer-1 mix (t=7 only, closed-form state) =================
    launch_mix(T_DIM - 1, hpack1, wmix1p, P1);
    reduceN_kernel<4><<<gRed, 256, 0, stream>>>(part, b_mix1, xsr_t, out1_b, V_DIM);

    // ================= head =================
    gemm16_kernel<1, 4, false><<<cdiv(V_DIM,32), 512, 0, stream>>>(
        out1_b, woutp, b_out, (float*)d_out, V_DIM, 256);
}

// Round 2
// 1408.053 us; speedup vs baseline: 1.2419x; 1.0961x over previous
//
#include <hip/hip_runtime.h>
#include <cstdint>
#include <cstddef>

#define T_DIM 8
#define V_DIM 10000
#define E_DIM 100000
#define M_ALL (T_DIM * V_DIM)

typedef __attribute__((ext_vector_type(8))) short short8;
typedef __attribute__((ext_vector_type(4))) float floatx4;

__device__ __forceinline__ unsigned int f2bf(float f) {
    union { float f; unsigned int u; } v; v.f = f;
    unsigned int u = v.u;
    u = u + 0x7FFFu + ((u >> 16) & 1u);   // RNE
    return u >> 16;
}
__device__ __forceinline__ float bf2f(unsigned int s) {
    union { unsigned int u; float f; } v; v.u = s << 16;
    return v.f;
}
__device__ __forceinline__ short8 relu8(short8 x) {
    const short8 z = {0,0,0,0,0,0,0,0};
    return __builtin_elementwise_max(x, z);   // v_pk_max_i16: bf16 relu on bit pattern
}
union PK { uint4 u; short8 s; };

// ---- pack fp32 weight [K,Nw] into MFMA B-fragment order inside a concat buffer
// frag index fo = (kt + kt_off) * NTN_tot + nt_off + nt
__global__ void pack_b_kernel(const float* __restrict__ w, unsigned short* __restrict__ out,
                              int K, int Nw, int NTN_tot, int nt_off, int kt_off) {
    int tid = blockIdx.x * blockDim.x + threadIdx.x;
    int total = (K >> 5) * (Nw >> 4) * 64;
    if (tid >= total) return;
    int lane = tid & 63;
    int f = tid >> 6;
    int ntn_w = Nw >> 4;
    int nt = f % ntn_w;
    int kt = f / ntn_w;
    int kbase = kt * 32 + ((lane >> 4) << 3);
    int n = nt * 16 + (lane & 15);
    unsigned int vals[8];
#pragma unroll
    for (int j = 0; j < 8; ++j)
        vals[j] = f2bf(w[(size_t)(kbase + j) * Nw + n]);
    uint4 pk;
    pk.x = vals[0] | (vals[1] << 16);
    pk.y = vals[2] | (vals[3] << 16);
    pk.z = vals[4] | (vals[5] << 16);
    pk.w = vals[6] | (vals[7] << 16);
    size_t fo = (size_t)(kt + kt_off) * NTN_tot + nt_off + nt;
    *(uint4*)(out + (fo * 64 + lane) * 8) = pk;
}

// ---- token mixer ----
__global__ void token_mix_kernel(const float* __restrict__ xs, const float* __restrict__ w_pre,
                                 const float* __restrict__ b_pre, unsigned short* __restrict__ ob) {
    const int S = V_DIM * 128;
    int tid = blockIdx.x * blockDim.x + threadIdx.x;
    if (tid >= T_DIM * S / 4) return;
    int e = tid * 4;
    int t = e / S;
    int c = e & 127;
    floatx4 xm = {0.f,0.f,0.f,0.f}, xp = {0.f,0.f,0.f,0.f};
    floatx4 x0 = *(const floatx4*)(xs + e);
    if (t > 0)          xm = *(const floatx4*)(xs + e - S);
    if (t < T_DIM - 1)  xp = *(const floatx4*)(xs + e + S);
    uint2 p; unsigned int b[4];
#pragma unroll
    for (int j = 0; j < 4; ++j) {
        int cc = c + j;
        float r = xm[j]*w_pre[cc*3+0] + x0[j]*w_pre[cc*3+1] + xp[j]*w_pre[cc*3+2] + b_pre[cc];
        b[j] = f2bf(r);
    }
    p.x = b[0] | (b[1] << 16);
    p.y = b[2] | (b[3] << 16);
    *(uint2*)(ob + e) = p;
}

// ---- P0[d][k] = B0[k]*lam0^d ; P1[d][k] = B1[k]*lam1^d  (d = 0..7) ----
__global__ void lamP_kernel(const float* __restrict__ a0, const float* __restrict__ a1,
                            const float* __restrict__ B0, const float* __restrict__ B1,
                            float* __restrict__ P0, float* __restrict__ P1) {
    int i = blockIdx.x * blockDim.x + threadIdx.x;
    if (i >= 4096) return;
    float l0 = expf(-expf(a0[i]));
    float l1 = expf(-expf(a1[i]));
    float p0 = B0[i], p1 = B1[i];
#pragma unroll
    for (int d = 0; d < 8; ++d) {
        P0[d * 4096 + i] = p0;
        P1[d * 4096 + i] = p1;
        p0 *= l0; p1 *= l1;
    }
}

// ---- bias prep: bcat = [b_sage | 0] per layer; bmt = b_mix + b_res ----
__global__ void bias_prep_kernel(const float* __restrict__ bs0, const float* __restrict__ bs1,
                                 const float* __restrict__ bm0, const float* __restrict__ br0,
                                 const float* __restrict__ bm1, const float* __restrict__ br1,
                                 float* __restrict__ bcat0, float* __restrict__ bcat1,
                                 float* __restrict__ bmt0, float* __restrict__ bmt1) {
    int i = blockIdx.x * blockDim.x + threadIdx.x;
    if (i < 512) {
        bcat0[i] = (i < 256) ? bs0[i] : 0.f;
        bcat1[i] = (i < 256) ? bs1[i] : 0.f;
    }
    if (i < 256) {
        bmt0[i] = bm0[i] + br0[i];
        bmt1[i] = bm1[i] + br1[i];
    }
}

// ================= CSR build =================
__global__ void deg_kernel(const int* __restrict__ ei, int* __restrict__ deg_cnt) {
    int tid = blockIdx.x * blockDim.x + threadIdx.x;
    if (tid >= T_DIM * E_DIM) return;
    int t = tid / E_DIM;
    int e = tid - t * E_DIM;
    int dst = ei[(size_t)t * 2 * E_DIM + E_DIM + e];
    if ((unsigned)dst < V_DIM) atomicAdd(deg_cnt + t * V_DIM + dst, 1);
}

__global__ void invdeg_kernel(const int* __restrict__ deg_cnt, float* __restrict__ inv) {
    int tid = blockIdx.x * blockDim.x + threadIdx.x;
    if (tid >= T_DIM * V_DIM) return;
    inv[tid] = 1.0f / (float)max(deg_cnt[tid], 1);
}

__global__ __launch_bounds__(1024)
void scan_kernel(const int* __restrict__ deg_cnt, int* __restrict__ rowptr) {
    __shared__ int sums[1024];
    int t = blockIdx.x;
    const int* d = deg_cnt + t * V_DIM;
    int* rp = rowptr + t * (V_DIM + 1);
    int tid = threadIdx.x;
    int base = tid * 10;
    int loc[10]; int s = 0;
#pragma unroll
    for (int j = 0; j < 10; ++j) {
        int v = base + j;
        int x = (v < V_DIM) ? d[v] : 0;
        loc[j] = s; s += x;
    }
    sums[tid] = s;
    __syncthreads();
    for (int o = 1; o < 1024; o <<= 1) {
        int v = (tid >= o) ? sums[tid - o] : 0;
        __syncthreads();
        sums[tid] += v;
        __syncthreads();
    }
    int prev = (tid == 0) ? 0 : sums[tid - 1];
#pragma unroll
    for (int j = 0; j < 10; ++j) {
        int v = base + j;
        if (v < V_DIM) rp[v] = prev + loc[j];
    }
    if (tid == 1023) rp[V_DIM] = sums[1023];
}

__global__ void fill_kernel(const int* __restrict__ ei, const int* __restrict__ rowptr,
                            int* __restrict__ fill_cnt, int* __restrict__ srcs) {
    int tid = blockIdx.x * blockDim.x + threadIdx.x;
    if (tid >= T_DIM * E_DIM) return;
    int t = tid / E_DIM;
    int e = tid - t * E_DIM;
    const int* eit = ei + (size_t)t * 2 * E_DIM;
    int src = eit[e];
    int dst = eit[E_DIM + e];
    if ((unsigned)src >= V_DIM || (unsigned)dst >= V_DIM) return;
    int pos = rowptr[t * (V_DIM + 1) + dst] + atomicAdd(fill_cnt + t * V_DIM + dst, 1);
    srcs[(size_t)t * E_DIM + pos] = src;
}

// ---- batched gather + slot-pack over all t: h = hb + (sum xn[src])*invdeg -> hpack[v][c][t]
__global__ void gather_pack_kernel(const unsigned short* __restrict__ xn, const int* __restrict__ srcs,
                                   const int* __restrict__ rowptr, const float* __restrict__ invdeg,
                                   const unsigned short* __restrict__ hb,
                                   unsigned short* __restrict__ hpack) {
    int gw = (blockIdx.x * blockDim.x + threadIdx.x) >> 6;
    int lane = threadIdx.x & 63;
    if (gw >= T_DIM * V_DIM) return;
    int t = gw / V_DIM;
    int v = gw - t * V_DIM;
    const int* rp = rowptr + t * (V_DIM + 1);
    int beg = rp[v], end = rp[v + 1];
    const int* st = srcs + (size_t)t * E_DIM;
    const unsigned short* xnt = xn + (size_t)t * V_DIM * 256;
    float a0 = 0.f, a1 = 0.f, a2 = 0.f, a3 = 0.f;
    for (int i = beg; i < end; ++i) {
        int s = st[i];
        uint2 p = *(const uint2*)(xnt + (size_t)s * 256 + lane * 4);
        a0 += bf2f(p.x & 0xffffu);
        a1 += bf2f(p.x >> 16);
        a2 += bf2f(p.y & 0xffffu);
        a3 += bf2f(p.y >> 16);
    }
    float inv = invdeg[t * V_DIM + v];
    uint2 h = *(const uint2*)(hb + ((size_t)t * V_DIM + v) * 256 + lane * 4);
    a0 = a0 * inv + bf2f(h.x & 0xffffu);
    a1 = a1 * inv + bf2f(h.x >> 16);
    a2 = a2 * inv + bf2f(h.y & 0xffffu);
    a3 = a3 * inv + bf2f(h.y >> 16);
    unsigned short* op = hpack + (size_t)v * 2048 + (size_t)(lane * 4) * 8 + t;
    op[0]  = (unsigned short)f2bf(a0);
    op[8]  = (unsigned short)f2bf(a1);
    op[16] = (unsigned short)f2bf(a2);
    op[24] = (unsigned short)f2bf(a3);
}

// ---- batched cat GEMM over all t: x @ [w_self|w_neigh]; region 0 -> d_self, 1 -> d_xn
template<int KT>
__global__ __launch_bounds__(256, 4)
void gemm_cat2_kernel(const unsigned short* __restrict__ A, const unsigned short* __restrict__ Bp,
                      const float* __restrict__ bias, unsigned short* __restrict__ d_self,
                      unsigned short* __restrict__ d_xn, int M) {
    const int w = threadIdx.x >> 6, lane = threadIdx.x & 63;
    const int quad = lane >> 4, l16 = lane & 15;
    const int region = blockIdx.x;
    const int m0 = blockIdx.y * 64;
    constexpr int K = KT * 32;
    floatx4 acc[4][4];
#pragma unroll
    for (int a = 0; a < 4; ++a)
#pragma unroll
        for (int b = 0; b < 4; ++b) acc[a][b] = (floatx4){0.f,0.f,0.f,0.f};
    const unsigned short* arow[4];
#pragma unroll
    for (int mi = 0; mi < 4; ++mi) {
        int r = m0 + mi * 16 + l16;
        if (r > M - 1) r = M - 1;
        arow[mi] = A + (size_t)r * K + quad * 8;
    }
    const unsigned short* bptr = Bp + ((size_t)(region * 16 + w * 4) * 64 + lane) * 8;
#pragma unroll
    for (int kt = 0; kt < KT; ++kt) {
        short8 bfr[4];
#pragma unroll
        for (int i = 0; i < 4; ++i) bfr[i] = *(const short8*)(bptr + i * 512);
        short8 af[4];
#pragma unroll
        for (int mi = 0; mi < 4; ++mi) af[mi] = *(const short8*)(arow[mi]);
#pragma unroll
        for (int mi = 0; mi < 4; ++mi)
#pragma unroll
            for (int i = 0; i < 4; ++i)
                acc[mi][i] = __builtin_amdgcn_mfma_f32_16x16x32_bf16(af[mi], bfr[i], acc[mi][i], 0, 0, 0);
        bptr += 32 * 512;
#pragma unroll
        for (int mi = 0; mi < 4; ++mi) arow[mi] += 32;
    }
#pragma unroll
    for (int mi = 0; mi < 4; ++mi) {
        int rbase = m0 + mi * 16 + quad * 4;
#pragma unroll
        for (int i = 0; i < 4; ++i) {
            int lcol = w * 64 + i * 16 + l16;
            float b = bias[region * 256 + lcol];
#pragma unroll
            for (int rr = 0; rr < 4; ++rr) {
                int row = rbase + rr;
                if (row < M) {
                    float v = acc[mi][i][rr] + b;
                    size_t off = (size_t)row * 256 + lcol;
                    if (region == 0) d_self[off] = (unsigned short)f2bf(v);
                    else             d_xn[off]  = (unsigned short)f2bf(v);
                }
            }
        }
    }
}

// ---- fused closed-form SSM + full-K mix GEMM + residual GEMM + bias, batched over t ----
// MI = rows/16 per block. K = 4096 (mix) + KRT*32 (residual via appended w_res kts).
// Phase 1 (per 256-k phase): 256 threads compute each state exactly once (8-tau
// predicated on tau<=t), relu+pack bf16 -> LDS A-fragments.
// Phase 2: MFMA from LDS. Residual tail: A read direct from global (bf16 rows).
// Epilogue: out = f2bf(acc + b_mix + b_res) -> bf16, no split-K partials.
template<int MI, int KRT, bool BATCH>
__global__ __launch_bounds__(256, 4)
void gemm_mix_cf5_kernel(const unsigned short* __restrict__ hp,   // hpack [V][256][8]
                         const unsigned short* __restrict__ Bp,   // packed [w_mix ; w_res]
                         const unsigned short* __restrict__ Ares, // residual A rows (bf16)
                         const float* __restrict__ P,             // [8][4096]
                         const float* __restrict__ bias,          // [256] = b_mix + b_res
                         unsigned short* __restrict__ out) {
    constexpr int KR = KRT * 32;
    __shared__ __align__(16) unsigned short Afrag[8 * MI * 64 * 8];
    const int tid = threadIdx.x;
    const int w = tid >> 6, lane = tid & 63;
    const int quad = lane >> 4, l16 = lane & 15;
    const int t    = BATCH ? blockIdx.x : (T_DIM - 1);
    const int mblk = BATCH ? blockIdx.y : blockIdx.x;
    const int m0 = mblk * (MI * 16);
    const size_t rowoff = BATCH ? (size_t)t * V_DIM : 0;
    // phase-1 work assignment
    const int kt1 = tid >> 5;            // 0..7  kt within phase
    const int kq  = (tid >> 3) & 3;      // 0..3  k-quad (8 k)
    const int rsel= tid & 7;             // 0..7  row class (stride 8)

    floatx4 acc[MI][4];
#pragma unroll
    for (int a = 0; a < MI; ++a)
#pragma unroll
        for (int b = 0; b < 4; ++b) acc[a][b] = (floatx4){0.f,0.f,0.f,0.f};

    const unsigned short* bptr = Bp + ((size_t)(w * 4) * 64 + lane) * 8;

    for (int p = 0; p < 16; ++p) {
        // ---- phase 1: cooperative state compute -> Afrag ----
        const int kg = p * 256 + kt1 * 32 + kq * 8;   // global k
        const int hh = kg >> 4;                        // h channel pair base
        floatx4 p0r[8], p1r[8];
#pragma unroll
        for (int tau = 0; tau < 8; ++tau) {
            int d = t - tau; if (d < 0) d = 0;        // clamped; masked by hv=0
            const float* Pd = P + (size_t)d * 4096 + kg;
            p0r[tau] = *(const floatx4*)Pd;
            p1r[tau] = *(const floatx4*)(Pd + 4);
        }
        const int abase = (kt1 * MI) * 64 + kq * 16;
#pragma unroll
        for (int g = 0; g < 2 * MI; ++g) {
            int r = rsel + g * 8;                     // block-local row
            int rg = m0 + r; if (rg > V_DIM - 1) rg = V_DIM - 1;
            PK h8; h8.u = *(const uint4*)(hp + (size_t)rg * 2048 + hh * 8);
            float sv[8];
#pragma unroll
            for (int j = 0; j < 8; ++j) sv[j] = 0.f;
#pragma unroll
            for (int tau = 0; tau < 8; ++tau) {
                float hv = bf2f((unsigned int)(unsigned short)h8.s[tau]);
                hv = (tau <= t) ? hv : 0.f;           // folds away for !BATCH
#pragma unroll
                for (int j = 0; j < 4; ++j) {
                    sv[j]     += hv * p0r[tau][j];
                    sv[4 + j] += hv * p1r[tau][j];
                }
            }
            PK cv;
            cv.u.x = f2bf(sv[0]) | (f2bf(sv[1]) << 16);
            cv.u.y = f2bf(sv[2]) | (f2bf(sv[3]) << 16);
            cv.u.z = f2bf(sv[4]) | (f2bf(sv[5]) << 16);
            cv.u.w = f2bf(sv[6]) | (f2bf(sv[7]) << 16);
            PK st; st.s = relu8(cv.s);
            int mi = r >> 4, rl = r & 15;
            *(uint4*)(Afrag + (size_t)(abase + mi * 64 + rl) * 8) = st.u;
        }
        __syncthreads();
        // ---- phase 2: MFMA over this phase's 8 kt ----
#pragma unroll
        for (int kt = 0; kt < 8; ++kt) {
            short8 bfr[4];
#pragma unroll
            for (int i = 0; i < 4; ++i) bfr[i] = *(const short8*)(bptr + i * 512);
            short8 af[MI];
#pragma unroll
            for (int mi = 0; mi < MI; ++mi)
                af[mi] = *(const short8*)(Afrag + (size_t)((kt * MI + mi) * 64 + lane) * 8);
#pragma unroll
            for (int mi = 0; mi < MI; ++mi)
#pragma unroll
                for (int i = 0; i < 4; ++i)
                    acc[mi][i] = __builtin_amdgcn_mfma_f32_16x16x32_bf16(af[mi], bfr[i], acc[mi][i], 0, 0, 0);
            bptr += 16 * 512;
        }
        __syncthreads();
    }
    // ---- residual tail: acc += x @ w_res (A direct from global) ----
    const unsigned short* ar[MI];
#pragma unroll
    for (int mi = 0; mi < MI; ++mi) {
        int r = m0 + mi * 16 + l16; if (r > V_DIM - 1) r = V_DIM - 1;
        ar[mi] = Ares + (rowoff + (size_t)r) * KR + quad * 8;
    }
#pragma unroll
    for (int ktr = 0; ktr < KRT; ++ktr) {
        short8 bfr[4];
#pragma unroll
        for (int i = 0; i < 4; ++i) bfr[i] = *(const short8*)(bptr + i * 512);
#pragma unroll
        for (int mi = 0; mi < MI; ++mi) {
            short8 af = *(const short8*)(ar[mi] + ktr * 32);
#pragma unroll
            for (int i = 0; i < 4; ++i)
                acc[mi][i] = __builtin_amdgcn_mfma_f32_16x16x32_bf16(af, bfr[i], acc[mi][i], 0, 0, 0);
        }
        bptr += 16 * 512;
    }
    // ---- epilogue: bias + bf16 store ----
#pragma unroll
    for (int mi = 0; mi < MI; ++mi) {
        int rbase = m0 + mi * 16 + quad * 4;
#pragma unroll
        for (int i = 0; i < 4; ++i) {
            int col = w * 64 + i * 16 + l16;
            float b = bias[col];
#pragma unroll
            for (int rr = 0; rr < 4; ++rr) {
                int row = rbase + rr;
                if (row < V_DIM)
                    out[(rowoff + (size_t)row) * 256 + col] = (unsigned short)f2bf(acc[mi][i][rr] + b);
            }
        }
    }
}

// ---- small GEMM (head): 32-row blocks, 8 waves ----
template<int NT, int NTN_TOT, bool RELU>
__global__ __launch_bounds__(512)
void gemm16_kernel(const unsigned short* __restrict__ A, const unsigned short* __restrict__ Bp,
                   const float* __restrict__ bias, float* __restrict__ outF, int M, int K) {
    const int w = threadIdx.x >> 6, lane = threadIdx.x & 63;
    const int quad = lane >> 4, l16 = lane & 15;
    const int rowgrp = w >> 2, nchunk = w & 3;
    const int m0 = blockIdx.x * 32 + rowgrp * 16;
    const int ntb = nchunk * NT;
    constexpr int Ntot = NTN_TOT * 16;
    floatx4 acc[NT];
#pragma unroll
    for (int i = 0; i < NT; ++i) acc[i] = (floatx4){0.f,0.f,0.f,0.f};
    int r = m0 + l16; if (r > M - 1) r = M - 1;
    const unsigned short* arow = A + (size_t)r * K + quad * 8;
    const int ksteps = K >> 5;
    for (int kt = 0; kt < ksteps; ++kt) {
        short8 af = *(const short8*)(arow + kt * 32);
        if (RELU) af = relu8(af);
#pragma unroll
        for (int i = 0; i < NT; ++i) {
            short8 bf = *(const short8*)(Bp + ((size_t)(kt * NTN_TOT + ntb + i) * 64 + lane) * 8);
            acc[i] = __builtin_amdgcn_mfma_f32_16x16x32_bf16(af, bf, acc[i], 0, 0, 0);
        }
    }
    const int rbase = m0 + quad * 4;
#pragma unroll
    for (int i = 0; i < NT; ++i) {
        int col = (ntb + i) * 16 + l16;
        float b = bias[col];
#pragma unroll
        for (int rr = 0; rr < 4; ++rr) {
            int row = rbase + rr;
            if (row < M)
                outF[(size_t)row * Ntot + col] = acc[i][rr] + b;
        }
    }
}

extern "C" void kernel_launch(void* const* d_in, const int* in_sizes, int n_in,
                              void* d_out, int out_size, void* d_ws, size_t ws_size,
                              hipStream_t stream) {
    const float* xs      = (const float*)d_in[0];
    const int*   ei      = (const int*)d_in[1];
    const float* w_pre   = (const float*)d_in[2];
    const float* b_pre   = (const float*)d_in[3];
    const float* w_res0  = (const float*)d_in[4];
    const float* b_res0  = (const float*)d_in[5];
    const float* w_self0 = (const float*)d_in[6];
    const float* w_neigh0= (const float*)d_in[7];
    const float* b_sage0 = (const float*)d_in[8];
    const float* a_log0  = (const float*)d_in[9];
    const float* B0      = (const float*)d_in[10];
    const float* w_mix0  = (const float*)d_in[11];
    const float* b_mix0  = (const float*)d_in[12];
    const float* w_res1  = (const float*)d_in[13];
    const float* b_res1  = (const float*)d_in[14];
    const float* w_self1 = (const float*)d_in[15];
    const float* w_neigh1= (const float*)d_in[16];
    const float* b_sage1 = (const float*)d_in[17];
    const float* a_log1  = (const float*)d_in[18];
    const float* B1      = (const float*)d_in[19];
    const float* w_mix1  = (const float*)d_in[20];
    const float* b_mix1  = (const float*)d_in[21];
    const float* w_out   = (const float*)d_in[22];
    const float* b_out   = (const float*)d_in[23];

    char* wsB = (char*)d_ws;
    size_t off = 0;
    auto alloc = [&](size_t bytes) {
        char* p = wsB + off;
        off += (bytes + 255) & ~(size_t)255;
        return p;
    };
    unsigned short* x0b   = (unsigned short*)alloc((size_t)M_ALL * 128 * 2);   // token-mixed input, all t
    unsigned short* hA    = (unsigned short*)alloc((size_t)M_ALL * 256 * 2);   // self part (both layers)
    unsigned short* hB    = (unsigned short*)alloc((size_t)M_ALL * 256 * 2);   // neigh part (both layers)
    unsigned short* hpack = (unsigned short*)alloc((size_t)V_DIM * 2048 * 2);  // [V][256][8] (both layers)
    unsigned short* x1b   = (unsigned short*)alloc((size_t)M_ALL * 256 * 2);   // layer-0 output, all t
    unsigned short* out1_b= (unsigned short*)alloc((size_t)V_DIM * 256 * 2);
    int*            deg_cnt = (int*)alloc((size_t)T_DIM * V_DIM * 4);
    float*          invdeg  = (float*)alloc((size_t)T_DIM * V_DIM * 4);
    int*            rowptr  = (int*)alloc((size_t)T_DIM * (V_DIM + 1) * 4);
    int*            fill_cnt= (int*)alloc((size_t)T_DIM * V_DIM * 4);
    int*            srcs    = (int*)alloc((size_t)T_DIM * E_DIM * 4);
    float*          P0    = (float*)alloc(8 * 4096 * 4);
    float*          P1    = (float*)alloc(8 * 4096 * 4);
    float*          bcat0 = (float*)alloc(512 * 4);
    float*          bcat1 = (float*)alloc(512 * 4);
    float*          bmt0  = (float*)alloc(256 * 4);
    float*          bmt1  = (float*)alloc(256 * 4);
    unsigned short* wcat0p= (unsigned short*)alloc((size_t)128 * 512 * 2);
    unsigned short* wcat1p= (unsigned short*)alloc((size_t)256 * 512 * 2);
    unsigned short* wmix0p= (unsigned short*)alloc((size_t)(4096 + 128) * 256 * 2);
    unsigned short* wmix1p= (unsigned short*)alloc((size_t)(4096 + 256) * 256 * 2);
    unsigned short* woutp = (unsigned short*)alloc((size_t)256 * 64 * 2);
    if (off > ws_size) return;   // fail cleanly, not a GPU fault

    auto cdiv = [](int a, int b) { return (a + b - 1) / b; };
    const int gMall = cdiv(M_ALL, 64);          // 1250
    const int gGat  = cdiv(M_ALL * 64, 256);    // 20000

    // ---- parameter prep ----
    lamP_kernel<<<16, 256, 0, stream>>>(a_log0, a_log1, B0, B1, P0, P1);
    bias_prep_kernel<<<2, 256, 0, stream>>>(b_sage0, b_sage1, b_mix0, b_res0, b_mix1, b_res1,
                                            bcat0, bcat1, bmt0, bmt1);
    // cat regions: [self | neigh], NTN_tot = 32
    pack_b_kernel<<<cdiv(4*16*64, 256), 256, 0, stream>>>(w_self0,  wcat0p, 128, 256, 32, 0, 0);
    pack_b_kernel<<<cdiv(4*16*64, 256), 256, 0, stream>>>(w_neigh0, wcat0p, 128, 256, 32, 16, 0);
    pack_b_kernel<<<cdiv(8*16*64, 256), 256, 0, stream>>>(w_self1,  wcat1p, 256, 256, 32, 0, 0);
    pack_b_kernel<<<cdiv(8*16*64, 256), 256, 0, stream>>>(w_neigh1, wcat1p, 256, 256, 32, 16, 0);
    // mix weights with residual appended along K (kt_off = 128)
    pack_b_kernel<<<cdiv(128*16*64, 256), 256, 0, stream>>>(w_mix0, wmix0p, 4096, 256, 16, 0, 0);
    pack_b_kernel<<<cdiv(4*16*64, 256),   256, 0, stream>>>(w_res0, wmix0p, 128,  256, 16, 0, 128);
    pack_b_kernel<<<cdiv(128*16*64, 256), 256, 0, stream>>>(w_mix1, wmix1p, 4096, 256, 16, 0, 0);
    pack_b_kernel<<<cdiv(8*16*64, 256),   256, 0, stream>>>(w_res1, wmix1p, 256,  256, 16, 0, 128);
    pack_b_kernel<<<cdiv(8*4*64, 256), 256, 0, stream>>>(w_out, woutp, 256, 64, 4, 0, 0);

    // ---- token mixer + CSR build ----
    token_mix_kernel<<<cdiv(T_DIM*V_DIM*128/4, 256), 256, 0, stream>>>(xs, w_pre, b_pre, x0b);
    hipMemsetAsync(deg_cnt, 0, (size_t)T_DIM * V_DIM * 4, stream);
    hipMemsetAsync(fill_cnt, 0, (size_t)T_DIM * V_DIM * 4, stream);
    deg_kernel<<<cdiv(T_DIM*E_DIM, 256), 256, 0, stream>>>(ei, deg_cnt);
    scan_kernel<<<T_DIM, 1024, 0, stream>>>(deg_cnt, rowptr);
    invdeg_kernel<<<cdiv(T_DIM*V_DIM, 256), 256, 0, stream>>>(deg_cnt, invdeg);
    fill_kernel<<<cdiv(T_DIM*E_DIM, 256), 256, 0, stream>>>(ei, rowptr, fill_cnt, srcs);

    // ================= layer 0 (batched over all t) =================
    gemm_cat2_kernel<4><<<dim3(2, gMall), 256, 0, stream>>>(x0b, wcat0p, bcat0, hA, hB, M_ALL);
    gather_pack_kernel<<<gGat, 256, 0, stream>>>(hB, srcs, rowptr, invdeg, hA, hpack);
    gemm_mix_cf5_kernel<4, 4, true><<<dim3(T_DIM, cdiv(V_DIM, 64)), 256, 0, stream>>>(
        hpack, wmix0p, x0b, P0, bmt0, x1b);

    // ================= layer 1 (batched over all t; mix only at t=7) =================
    gemm_cat2_kernel<8><<<dim3(2, gMall), 256, 0, stream>>>(x1b, wcat1p, bcat1, hA, hB, M_ALL);
    gather_pack_kernel<<<gGat, 256, 0, stream>>>(hB, srcs, rowptr, invdeg, hA, hpack);
    gemm_mix_cf5_kernel<1, 8, false><<<dim3(cdiv(V_DIM, 16), 1), 256, 0, stream>>>(
        hpack, wmix1p, x1b + (size_t)(T_DIM - 1) * V_DIM * 256, P1, bmt1, out1_b);

    // ================= head =================
    gemm16_kernel<1, 4, false><<<cdiv(V_DIM,32), 512, 0, stream>>>(
        out1_b, woutp, b_out, (float*)d_out, V_DIM, 256);
}

// Round 3
// 1034.497 us; speedup vs baseline: 1.6904x; 1.3611x over previous
//
#include <hip/hip_runtime.h>
#include <cstdint>
#include <cstddef>

#define T_DIM 8
#define V_DIM 10000
#define E_DIM 100000
#define M_ALL (T_DIM * V_DIM)

typedef __attribute__((ext_vector_type(8))) short short8;
typedef __attribute__((ext_vector_type(4))) float floatx4;

__device__ __forceinline__ unsigned int f2bf(float f) {
    union { float f; unsigned int u; } v; v.f = f;
    unsigned int u = v.u;
    u = u + 0x7FFFu + ((u >> 16) & 1u);   // RNE
    return u >> 16;
}
__device__ __forceinline__ float bf2f(unsigned int s) {
    union { unsigned int u; float f; } v; v.u = s << 16;
    return v.f;
}
__device__ __forceinline__ short8 relu8(short8 x) {
    const short8 z = {0,0,0,0,0,0,0,0};
    return __builtin_elementwise_max(x, z);   // v_pk_max_i16: bf16 relu on bit pattern
}
union PK { uint4 u; short8 s; };

// ---- pack fp32 weight [K,Nw] into MFMA B-fragment order inside a concat buffer
// frag index fo = (kt + kt_off) * NTN_tot + nt_off + nt
__global__ void pack_b_kernel(const float* __restrict__ w, unsigned short* __restrict__ out,
                              int K, int Nw, int NTN_tot, int nt_off, int kt_off) {
    int tid = blockIdx.x * blockDim.x + threadIdx.x;
    int total = (K >> 5) * (Nw >> 4) * 64;
    if (tid >= total) return;
    int lane = tid & 63;
    int f = tid >> 6;
    int ntn_w = Nw >> 4;
    int nt = f % ntn_w;
    int kt = f / ntn_w;
    int kbase = kt * 32 + ((lane >> 4) << 3);
    int n = nt * 16 + (lane & 15);
    unsigned int vals[8];
#pragma unroll
    for (int j = 0; j < 8; ++j)
        vals[j] = f2bf(w[(size_t)(kbase + j) * Nw + n]);
    uint4 pk;
    pk.x = vals[0] | (vals[1] << 16);
    pk.y = vals[2] | (vals[3] << 16);
    pk.z = vals[4] | (vals[5] << 16);
    pk.w = vals[6] | (vals[7] << 16);
    size_t fo = (size_t)(kt + kt_off) * NTN_tot + nt_off + nt;
    *(uint4*)(out + (fo * 64 + lane) * 8) = pk;
}

// ---- token mixer ----
__global__ void token_mix_kernel(const float* __restrict__ xs, const float* __restrict__ w_pre,
                                 const float* __restrict__ b_pre, unsigned short* __restrict__ ob) {
    const int S = V_DIM * 128;
    int tid = blockIdx.x * blockDim.x + threadIdx.x;
    if (tid >= T_DIM * S / 4) return;
    int e = tid * 4;
    int t = e / S;
    int c = e & 127;
    floatx4 xm = {0.f,0.f,0.f,0.f}, xp = {0.f,0.f,0.f,0.f};
    floatx4 x0 = *(const floatx4*)(xs + e);
    if (t > 0)          xm = *(const floatx4*)(xs + e - S);
    if (t < T_DIM - 1)  xp = *(const floatx4*)(xs + e + S);
    uint2 p; unsigned int b[4];
#pragma unroll
    for (int j = 0; j < 4; ++j) {
        int cc = c + j;
        float r = xm[j]*w_pre[cc*3+0] + x0[j]*w_pre[cc*3+1] + xp[j]*w_pre[cc*3+2] + b_pre[cc];
        b[j] = f2bf(r);
    }
    p.x = b[0] | (b[1] << 16);
    p.y = b[2] | (b[3] << 16);
    *(uint2*)(ob + e) = p;
}

// ---- lam0[k] = exp(-exp(a0[k])) ; P1[d][k] = B1[k]*lam1^d  (d = 0..7) ----
__global__ void lamP_kernel(const float* __restrict__ a0, const float* __restrict__ a1,
                            const float* __restrict__ B1,
                            float* __restrict__ lam0, float* __restrict__ P1) {
    int i = blockIdx.x * blockDim.x + threadIdx.x;
    if (i >= 4096) return;
    lam0[i] = expf(-expf(a0[i]));
    float l1 = expf(-expf(a1[i]));
    float p1 = B1[i];
#pragma unroll
    for (int d = 0; d < 8; ++d) {
        P1[d * 4096 + i] = p1;
        p1 *= l1;
    }
}

// ---- bias prep: bcat = [b_sage | 0] per layer; bmt = b_mix + b_res ----
__global__ void bias_prep_kernel(const float* __restrict__ bs0, const float* __restrict__ bs1,
                                 const float* __restrict__ bm0, const float* __restrict__ br0,
                                 const float* __restrict__ bm1, const float* __restrict__ br1,
                                 float* __restrict__ bcat0, float* __restrict__ bcat1,
                                 float* __restrict__ bmt0, float* __restrict__ bmt1) {
    int i = blockIdx.x * blockDim.x + threadIdx.x;
    if (i < 512) {
        bcat0[i] = (i < 256) ? bs0[i] : 0.f;
        bcat1[i] = (i < 256) ? bs1[i] : 0.f;
    }
    if (i < 256) {
        bmt0[i] = bm0[i] + br0[i];
        bmt1[i] = bm1[i] + br1[i];
    }
}

// ================= CSR build =================
__global__ void deg_kernel(const int* __restrict__ ei, int* __restrict__ deg_cnt) {
    int tid = blockIdx.x * blockDim.x + threadIdx.x;
    if (tid >= T_DIM * E_DIM) return;
    int t = tid / E_DIM;
    int e = tid - t * E_DIM;
    int dst = ei[(size_t)t * 2 * E_DIM + E_DIM + e];
    if ((unsigned)dst < V_DIM) atomicAdd(deg_cnt + t * V_DIM + dst, 1);
}

__global__ void invdeg_kernel(const int* __restrict__ deg_cnt, float* __restrict__ inv) {
    int tid = blockIdx.x * blockDim.x + threadIdx.x;
    if (tid >= T_DIM * V_DIM) return;
    inv[tid] = 1.0f / (float)max(deg_cnt[tid], 1);
}

__global__ __launch_bounds__(1024)
void scan_kernel(const int* __restrict__ deg_cnt, int* __restrict__ rowptr) {
    __shared__ int sums[1024];
    int t = blockIdx.x;
    const int* d = deg_cnt + t * V_DIM;
    int* rp = rowptr + t * (V_DIM + 1);
    int tid = threadIdx.x;
    int base = tid * 10;
    int loc[10]; int s = 0;
#pragma unroll
    for (int j = 0; j < 10; ++j) {
        int v = base + j;
        int x = (v < V_DIM) ? d[v] : 0;
        loc[j] = s; s += x;
    }
    sums[tid] = s;
    __syncthreads();
    for (int o = 1; o < 1024; o <<= 1) {
        int v = (tid >= o) ? sums[tid - o] : 0;
        __syncthreads();
        sums[tid] += v;
        __syncthreads();
    }
    int prev = (tid == 0) ? 0 : sums[tid - 1];
#pragma unroll
    for (int j = 0; j < 10; ++j) {
        int v = base + j;
        if (v < V_DIM) rp[v] = prev + loc[j];
    }
    if (tid == 1023) rp[V_DIM] = sums[1023];
}

__global__ void fill_kernel(const int* __restrict__ ei, const int* __restrict__ rowptr,
                            int* __restrict__ fill_cnt, int* __restrict__ srcs) {
    int tid = blockIdx.x * blockDim.x + threadIdx.x;
    if (tid >= T_DIM * E_DIM) return;
    int t = tid / E_DIM;
    int e = tid - t * E_DIM;
    const int* eit = ei + (size_t)t * 2 * E_DIM;
    int src = eit[e];
    int dst = eit[E_DIM + e];
    if ((unsigned)src >= V_DIM || (unsigned)dst >= V_DIM) return;
    int pos = rowptr[t * (V_DIM + 1) + dst] + atomicAdd(fill_cnt + t * V_DIM + dst, 1);
    srcs[(size_t)t * E_DIM + pos] = src;
}

// ---- batched gather + slot-pack over all t: h = hb + (sum xn[src])*invdeg -> hpack[v][c][t]
__global__ void gather_pack_kernel(const unsigned short* __restrict__ xn, const int* __restrict__ srcs,
                                   const int* __restrict__ rowptr, const float* __restrict__ invdeg,
                                   const unsigned short* __restrict__ hb,
                                   unsigned short* __restrict__ hpack) {
    int gw = (blockIdx.x * blockDim.x + threadIdx.x) >> 6;
    int lane = threadIdx.x & 63;
    if (gw >= T_DIM * V_DIM) return;
    int t = gw / V_DIM;
    int v = gw - t * V_DIM;
    const int* rp = rowptr + t * (V_DIM + 1);
    int beg = rp[v], end = rp[v + 1];
    const int* st = srcs + (size_t)t * E_DIM;
    const unsigned short* xnt = xn + (size_t)t * V_DIM * 256;
    float a0 = 0.f, a1 = 0.f, a2 = 0.f, a3 = 0.f;
    for (int i = beg; i < end; ++i) {
        int s = st[i];
        uint2 p = *(const uint2*)(xnt + (size_t)s * 256 + lane * 4);
        a0 += bf2f(p.x & 0xffffu);
        a1 += bf2f(p.x >> 16);
        a2 += bf2f(p.y & 0xffffu);
        a3 += bf2f(p.y >> 16);
    }
    float inv = invdeg[t * V_DIM + v];
    uint2 h = *(const uint2*)(hb + ((size_t)t * V_DIM + v) * 256 + lane * 4);
    a0 = a0 * inv + bf2f(h.x & 0xffffu);
    a1 = a1 * inv + bf2f(h.x >> 16);
    a2 = a2 * inv + bf2f(h.y & 0xffffu);
    a3 = a3 * inv + bf2f(h.y >> 16);
    unsigned short* op = hpack + (size_t)v * 2048 + (size_t)(lane * 4) * 8 + t;
    op[0]  = (unsigned short)f2bf(a0);
    op[8]  = (unsigned short)f2bf(a1);
    op[16] = (unsigned short)f2bf(a2);
    op[24] = (unsigned short)f2bf(a3);
}

// ---- batched cat GEMM over all t: x @ [w_self|w_neigh]; region 0 -> d_self, 1 -> d_xn
template<int KT>
__global__ __launch_bounds__(256, 4)
void gemm_cat2_kernel(const unsigned short* __restrict__ A, const unsigned short* __restrict__ Bp,
                      const float* __restrict__ bias, unsigned short* __restrict__ d_self,
                      unsigned short* __restrict__ d_xn, int M) {
    const int w = threadIdx.x >> 6, lane = threadIdx.x & 63;
    const int quad = lane >> 4, l16 = lane & 15;
    const int region = blockIdx.x;
    const int m0 = blockIdx.y * 64;
    constexpr int K = KT * 32;
    floatx4 acc[4][4];
#pragma unroll
    for (int a = 0; a < 4; ++a)
#pragma unroll
        for (int b = 0; b < 4; ++b) acc[a][b] = (floatx4){0.f,0.f,0.f,0.f};
    const unsigned short* arow[4];
#pragma unroll
    for (int mi = 0; mi < 4; ++mi) {
        int r = m0 + mi * 16 + l16;
        if (r > M - 1) r = M - 1;
        arow[mi] = A + (size_t)r * K + quad * 8;
    }
    const unsigned short* bptr = Bp + ((size_t)(region * 16 + w * 4) * 64 + lane) * 8;
#pragma unroll
    for (int kt = 0; kt < KT; ++kt) {
        short8 bfr[4];
#pragma unroll
        for (int i = 0; i < 4; ++i) bfr[i] = *(const short8*)(bptr + i * 512);
        short8 af[4];
#pragma unroll
        for (int mi = 0; mi < 4; ++mi) af[mi] = *(const short8*)(arow[mi]);
#pragma unroll
        for (int mi = 0; mi < 4; ++mi)
#pragma unroll
            for (int i = 0; i < 4; ++i)
                acc[mi][i] = __builtin_amdgcn_mfma_f32_16x16x32_bf16(af[mi], bfr[i], acc[mi][i], 0, 0, 0);
        bptr += 32 * 512;
#pragma unroll
        for (int mi = 0; mi < 4; ++mi) arow[mi] += 32;
    }
#pragma unroll
    for (int mi = 0; mi < 4; ++mi) {
        int rbase = m0 + mi * 16 + quad * 4;
#pragma unroll
        for (int i = 0; i < 4; ++i) {
            int lcol = w * 64 + i * 16 + l16;
            float b = bias[region * 256 + lcol];
#pragma unroll
            for (int rr = 0; rr < 4; ++rr) {
                int row = rbase + rr;
                if (row < M) {
                    float v = acc[mi][i][rr] + b;
                    size_t off = (size_t)row * 256 + lcol;
                    if (region == 0) d_self[off] = (unsigned short)f2bf(v);
                    else             d_xn[off]  = (unsigned short)f2bf(v);
                }
            }
        }
    }
}

// ---- layer-0 mix: recurrence SSM + mix GEMM + residual, ALL 8 t per block ----
// Block: 16 rows x 256 cols x 8 t. K = 4096 + KRT*32 (residual appended in Bp).
// 16 phases of 256 k: phase-1: 256 threads run the t-recurrence
// s(t)=lam*s(t-1)+h(t)*B for 8 k each x 2 octets (hpack read ONCE per (row,k)),
// relu+pack -> Afrag[kt][t][lane]. phase-2: MFMA; B-frags shared across 8 t.
// acc[8][4] = 128 VGPR; launch_bounds(256,2) -> 256-VGPR cap, no spill.
template<int KRT>
__global__ __launch_bounds__(256, 2)
void gemm_mix_rec_kernel(const unsigned short* __restrict__ hp,   // hpack [V][256][8]
                         const unsigned short* __restrict__ Bp,   // packed [w_mix ; w_res]
                         const unsigned short* __restrict__ Ares, // residual A rows [T][V][KRT*32]
                         const float* __restrict__ lam,           // [4096]
                         const float* __restrict__ Bv,            // [4096]
                         const float* __restrict__ bias,          // [256] = b_mix + b_res
                         unsigned short* __restrict__ out) {      // [T][V][256]
    constexpr int KR = KRT * 32;
    __shared__ __align__(16) unsigned short Afrag[8 * 8 * 64 * 8];   // 64 KiB: [kt][t][lane][8]
    const int tid = threadIdx.x;
    const int w = tid >> 6, lane = tid & 63;
    const int quad = lane >> 4, l16 = lane & 15;
    const int m0 = blockIdx.x * 16;
    // phase-1 assignment: row (tid&15) + two octets (tid>>4, +16)
    const int prow = tid & 15;
    const int oct0 = tid >> 4;           // 0..15; handles oct0 and oct0+16
    const int vr = m0 + prow;

    floatx4 acc[8][4];
#pragma unroll
    for (int t = 0; t < 8; ++t)
#pragma unroll
        for (int i = 0; i < 4; ++i) acc[t][i] = (floatx4){0.f,0.f,0.f,0.f};

    const unsigned short* bptr = Bp + ((size_t)(w * 4) * 64 + lane) * 8;

    for (int ph = 0; ph < 16; ++ph) {
        // ---- phase 1: recurrence states for all 8 t -> Afrag ----
#pragma unroll
        for (int oo = 0; oo < 2; ++oo) {
            const int o = oct0 + oo * 16;          // 0..31
            const int kt = o >> 2;                 // 0..7
            const int qo = o & 3;                  // k-quad in tile
            const int kg = ph * 256 + kt * 32 + qo * 8;
            const int ch = kg >> 4;
            PK h8; h8.u = *(const uint4*)(hp + (size_t)vr * 2048 + (size_t)ch * 8);
            floatx4 l0 = *(const floatx4*)(lam + kg);
            floatx4 l1 = *(const floatx4*)(lam + kg + 4);
            floatx4 b0 = *(const floatx4*)(Bv + kg);
            floatx4 b1 = *(const floatx4*)(Bv + kg + 4);
            float s0=0.f,s1=0.f,s2=0.f,s3=0.f,s4=0.f,s5=0.f,s6=0.f,s7=0.f;
            unsigned short* ap = Afrag + ((size_t)(kt * 8) * 64 + qo * 16 + prow) * 8;
#pragma unroll
            for (int t = 0; t < 8; ++t) {
                float hv = bf2f((unsigned int)(unsigned short)h8.s[t]);
                s0 = l0[0]*s0 + hv*b0[0];
                s1 = l0[1]*s1 + hv*b0[1];
                s2 = l0[2]*s2 + hv*b0[2];
                s3 = l0[3]*s3 + hv*b0[3];
                s4 = l1[0]*s4 + hv*b1[0];
                s5 = l1[1]*s5 + hv*b1[1];
                s6 = l1[2]*s6 + hv*b1[2];
                s7 = l1[3]*s7 + hv*b1[3];
                PK cv;
                cv.u.x = f2bf(s0) | (f2bf(s1) << 16);
                cv.u.y = f2bf(s2) | (f2bf(s3) << 16);
                cv.u.z = f2bf(s4) | (f2bf(s5) << 16);
                cv.u.w = f2bf(s6) | (f2bf(s7) << 16);
                PK st; st.s = relu8(cv.s);
                *(uint4*)(ap + (size_t)t * 512) = st.u;   // t*64 lanes*8 shorts
            }
        }
        __syncthreads();
        // ---- phase 2: MFMA over this phase's 8 kt; B-frag reused across 8 t ----
#pragma unroll
        for (int kt = 0; kt < 8; ++kt) {
            short8 bfr[4];
#pragma unroll
            for (int i = 0; i < 4; ++i) bfr[i] = *(const short8*)(bptr + i * 512);
#pragma unroll
            for (int t = 0; t < 8; ++t) {
                short8 af = *(const short8*)(Afrag + ((size_t)((kt * 8 + t) * 64 + lane)) * 8);
#pragma unroll
                for (int i = 0; i < 4; ++i)
                    acc[t][i] = __builtin_amdgcn_mfma_f32_16x16x32_bf16(af, bfr[i], acc[t][i], 0, 0, 0);
            }
            bptr += 16 * 512;
        }
        __syncthreads();
    }
    // ---- residual tail: acc[t] += x(t) @ w_res ----
#pragma unroll
    for (int ktr = 0; ktr < KRT; ++ktr) {
        short8 bfr[4];
#pragma unroll
        for (int i = 0; i < 4; ++i) bfr[i] = *(const short8*)(bptr + i * 512);
#pragma unroll
        for (int t = 0; t < 8; ++t) {
            const unsigned short* ar = Ares + ((size_t)t * V_DIM + (size_t)(m0 + l16)) * KR + ktr * 32 + quad * 8;
            short8 af = *(const short8*)ar;
#pragma unroll
            for (int i = 0; i < 4; ++i)
                acc[t][i] = __builtin_amdgcn_mfma_f32_16x16x32_bf16(af, bfr[i], acc[t][i], 0, 0, 0);
        }
        bptr += 16 * 512;
    }
    // ---- epilogue: bias + bf16 store, per t ----
#pragma unroll
    for (int t = 0; t < 8; ++t) {
#pragma unroll
        for (int i = 0; i < 4; ++i) {
            int col = w * 64 + i * 16 + l16;
            float b = bias[col];
#pragma unroll
            for (int rr = 0; rr < 4; ++rr) {
                int row = m0 + quad * 4 + rr;
                out[((size_t)t * V_DIM + row) * 256 + col] = (unsigned short)f2bf(acc[t][i][rr] + b);
            }
        }
    }
}

// ---- layer-1 mix (t=7 only): closed-form SSM + full-K mix GEMM + residual ----
template<int MI, int KRT>
__global__ __launch_bounds__(256, 2)
void gemm_mix_cf5_kernel(const unsigned short* __restrict__ hp,   // hpack [V][256][8]
                         const unsigned short* __restrict__ Bp,   // packed [w_mix ; w_res]
                         const unsigned short* __restrict__ Ares, // residual A rows (bf16)
                         const float* __restrict__ P,             // [8][4096]
                         const float* __restrict__ bias,          // [256] = b_mix + b_res
                         unsigned short* __restrict__ out) {
    constexpr int KR = KRT * 32;
    constexpr int TT = T_DIM - 1;
    __shared__ __align__(16) unsigned short Afrag[8 * MI * 64 * 8];
    const int tid = threadIdx.x;
    const int w = tid >> 6, lane = tid & 63;
    const int quad = lane >> 4, l16 = lane & 15;
    const int m0 = blockIdx.x * (MI * 16);
    const int kt1 = tid >> 5;            // 0..7  kt within phase
    const int kq  = (tid >> 3) & 3;      // 0..3  k-quad (8 k)
    const int rsel= tid & 7;             // 0..7  row class (stride 8)

    floatx4 acc[MI][4];
#pragma unroll
    for (int a = 0; a < MI; ++a)
#pragma unroll
        for (int b = 0; b < 4; ++b) acc[a][b] = (floatx4){0.f,0.f,0.f,0.f};

    const unsigned short* bptr = Bp + ((size_t)(w * 4) * 64 + lane) * 8;

    for (int p = 0; p < 16; ++p) {
        const int kg = p * 256 + kt1 * 32 + kq * 8;   // global k
        const int hh = kg >> 4;
        floatx4 p0r[8], p1r[8];
#pragma unroll
        for (int tau = 0; tau < 8; ++tau) {
            const float* Pd = P + (size_t)(TT - tau) * 4096 + kg;
            p0r[tau] = *(const floatx4*)Pd;
            p1r[tau] = *(const floatx4*)(Pd + 4);
        }
        const int abase = (kt1 * MI) * 64 + kq * 16;
#pragma unroll
        for (int g = 0; g < 2 * MI; ++g) {
            int r = rsel + g * 8;
            int rg = m0 + r; if (rg > V_DIM - 1) rg = V_DIM - 1;
            PK h8; h8.u = *(const uint4*)(hp + (size_t)rg * 2048 + hh * 8);
            float sv[8];
#pragma unroll
            for (int j = 0; j < 8; ++j) sv[j] = 0.f;
#pragma unroll
            for (int tau = 0; tau < 8; ++tau) {
                float hv = bf2f((unsigned int)(unsigned short)h8.s[tau]);
#pragma unroll
                for (int j = 0; j < 4; ++j) {
                    sv[j]     += hv * p0r[tau][j];
                    sv[4 + j] += hv * p1r[tau][j];
                }
            }
            PK cv;
            cv.u.x = f2bf(sv[0]) | (f2bf(sv[1]) << 16);
            cv.u.y = f2bf(sv[2]) | (f2bf(sv[3]) << 16);
            cv.u.z = f2bf(sv[4]) | (f2bf(sv[5]) << 16);
            cv.u.w = f2bf(sv[6]) | (f2bf(sv[7]) << 16);
            PK st; st.s = relu8(cv.s);
            int mi = r >> 4, rl = r & 15;
            *(uint4*)(Afrag + (size_t)(abase + mi * 64 + rl) * 8) = st.u;
        }
        __syncthreads();
#pragma unroll
        for (int kt = 0; kt < 8; ++kt) {
            short8 bfr[4];
#pragma unroll
            for (int i = 0; i < 4; ++i) bfr[i] = *(const short8*)(bptr + i * 512);
            short8 af[MI];
#pragma unroll
            for (int mi = 0; mi < MI; ++mi)
                af[mi] = *(const short8*)(Afrag + (size_t)((kt * MI + mi) * 64 + lane) * 8);
#pragma unroll
            for (int mi = 0; mi < MI; ++mi)
#pragma unroll
                for (int i = 0; i < 4; ++i)
                    acc[mi][i] = __builtin_amdgcn_mfma_f32_16x16x32_bf16(af[mi], bfr[i], acc[mi][i], 0, 0, 0);
            bptr += 16 * 512;
        }
        __syncthreads();
    }
    // ---- residual tail ----
    const unsigned short* ar[MI];
#pragma unroll
    for (int mi = 0; mi < MI; ++mi) {
        int r = m0 + mi * 16 + l16; if (r > V_DIM - 1) r = V_DIM - 1;
        ar[mi] = Ares + (size_t)r * KR + quad * 8;
    }
#pragma unroll
    for (int ktr = 0; ktr < KRT; ++ktr) {
        short8 bfr[4];
#pragma unroll
        for (int i = 0; i < 4; ++i) bfr[i] = *(const short8*)(bptr + i * 512);
#pragma unroll
        for (int mi = 0; mi < MI; ++mi) {
            short8 af = *(const short8*)(ar[mi] + ktr * 32);
#pragma unroll
            for (int i = 0; i < 4; ++i)
                acc[mi][i] = __builtin_amdgcn_mfma_f32_16x16x32_bf16(af, bfr[i], acc[mi][i], 0, 0, 0);
        }
        bptr += 16 * 512;
    }
    // ---- epilogue ----
#pragma unroll
    for (int mi = 0; mi < MI; ++mi) {
        int rbase = m0 + mi * 16 + quad * 4;
#pragma unroll
        for (int i = 0; i < 4; ++i) {
            int col = w * 64 + i * 16 + l16;
            float b = bias[col];
#pragma unroll
            for (int rr = 0; rr < 4; ++rr) {
                int row = rbase + rr;
                if (row < V_DIM)
                    out[(size_t)row * 256 + col] = (unsigned short)f2bf(acc[mi][i][rr] + b);
            }
        }
    }
}

// ---- small GEMM (head): 32-row blocks, 8 waves ----
template<int NT, int NTN_TOT, bool RELU>
__global__ __launch_bounds__(512)
void gemm16_kernel(const unsigned short* __restrict__ A, const unsigned short* __restrict__ Bp,
                   const float* __restrict__ bias, float* __restrict__ outF, int M, int K) {
    const int w = threadIdx.x >> 6, lane = threadIdx.x & 63;
    const int quad = lane >> 4, l16 = lane & 15;
    const int rowgrp = w >> 2, nchunk = w & 3;
    const int m0 = blockIdx.x * 32 + rowgrp * 16;
    const int ntb = nchunk * NT;
    constexpr int Ntot = NTN_TOT * 16;
    floatx4 acc[NT];
#pragma unroll
    for (int i = 0; i < NT; ++i) acc[i] = (floatx4){0.f,0.f,0.f,0.f};
    int r = m0 + l16; if (r > M - 1) r = M - 1;
    const unsigned short* arow = A + (size_t)r * K + quad * 8;
    const int ksteps = K >> 5;
    for (int kt = 0; kt < ksteps; ++kt) {
        short8 af = *(const short8*)(arow + kt * 32);
        if (RELU) af = relu8(af);
#pragma unroll
        for (int i = 0; i < NT; ++i) {
            short8 bf = *(const short8*)(Bp + ((size_t)(kt * NTN_TOT + ntb + i) * 64 + lane) * 8);
            acc[i] = __builtin_amdgcn_mfma_f32_16x16x32_bf16(af, bf, acc[i], 0, 0, 0);
        }
    }
    const int rbase = m0 + quad * 4;
#pragma unroll
    for (int i = 0; i < NT; ++i) {
        int col = (ntb + i) * 16 + l16;
        float b = bias[col];
#pragma unroll
        for (int rr = 0; rr < 4; ++rr) {
            int row = rbase + rr;
            if (row < M)
                outF[(size_t)row * Ntot + col] = acc[i][rr] + b;
        }
    }
}

extern "C" void kernel_launch(void* const* d_in, const int* in_sizes, int n_in,
                              void* d_out, int out_size, void* d_ws, size_t ws_size,
                              hipStream_t stream) {
    const float* xs      = (const float*)d_in[0];
    const int*   ei      = (const int*)d_in[1];
    const float* w_pre   = (const float*)d_in[2];
    const float* b_pre   = (const float*)d_in[3];
    const float* w_res0  = (const float*)d_in[4];
    const float* b_res0  = (const float*)d_in[5];
    const float* w_self0 = (const float*)d_in[6];
    const float* w_neigh0= (const float*)d_in[7];
    const float* b_sage0 = (const float*)d_in[8];
    const float* a_log0  = (const float*)d_in[9];
    const float* B0      = (const float*)d_in[10];
    const float* w_mix0  = (const float*)d_in[11];
    const float* b_mix0  = (const float*)d_in[12];
    const float* w_res1  = (const float*)d_in[13];
    const float* b_res1  = (const float*)d_in[14];
    const float* w_self1 = (const float*)d_in[15];
    const float* w_neigh1= (const float*)d_in[16];
    const float* b_sage1 = (const float*)d_in[17];
    const float* a_log1  = (const float*)d_in[18];
    const float* B1      = (const float*)d_in[19];
    const float* w_mix1  = (const float*)d_in[20];
    const float* b_mix1  = (const float*)d_in[21];
    const float* w_out   = (const float*)d_in[22];
    const float* b_out   = (const float*)d_in[23];

    char* wsB = (char*)d_ws;
    size_t off = 0;
    auto alloc = [&](size_t bytes) {
        char* p = wsB + off;
        off += (bytes + 255) & ~(size_t)255;
        return p;
    };
    unsigned short* x0b   = (unsigned short*)alloc((size_t)M_ALL * 128 * 2);   // token-mixed input, all t
    unsigned short* hA    = (unsigned short*)alloc((size_t)M_ALL * 256 * 2);   // self part (both layers)
    unsigned short* hB    = (unsigned short*)alloc((size_t)M_ALL * 256 * 2);   // neigh part (both layers)
    unsigned short* hpack = (unsigned short*)alloc((size_t)V_DIM * 2048 * 2);  // [V][256][8] (both layers)
    unsigned short* x1b   = (unsigned short*)alloc((size_t)M_ALL * 256 * 2);   // layer-0 output, all t
    unsigned short* out1_b= (unsigned short*)alloc((size_t)V_DIM * 256 * 2);
    int*            deg_cnt = (int*)alloc((size_t)T_DIM * V_DIM * 4);
    float*          invdeg  = (float*)alloc((size_t)T_DIM * V_DIM * 4);
    int*            rowptr  = (int*)alloc((size_t)T_DIM * (V_DIM + 1) * 4);
    int*            fill_cnt= (int*)alloc((size_t)T_DIM * V_DIM * 4);
    int*            srcs    = (int*)alloc((size_t)T_DIM * E_DIM * 4);
    float*          lam0  = (float*)alloc(4096 * 4);
    float*          P1    = (float*)alloc(8 * 4096 * 4);
    float*          bcat0 = (float*)alloc(512 * 4);
    float*          bcat1 = (float*)alloc(512 * 4);
    float*          bmt0  = (float*)alloc(256 * 4);
    float*          bmt1  = (float*)alloc(256 * 4);
    unsigned short* wcat0p= (unsigned short*)alloc((size_t)128 * 512 * 2);
    unsigned short* wcat1p= (unsigned short*)alloc((size_t)256 * 512 * 2);
    unsigned short* wmix0p= (unsigned short*)alloc((size_t)(4096 + 128) * 256 * 2);
    unsigned short* wmix1p= (unsigned short*)alloc((size_t)(4096 + 256) * 256 * 2);
    unsigned short* woutp = (unsigned short*)alloc((size_t)256 * 64 * 2);
    if (off > ws_size) return;   // fail cleanly, not a GPU fault

    auto cdiv = [](int a, int b) { return (a + b - 1) / b; };
    const int gMall = cdiv(M_ALL, 64);          // 1250
    const int gGat  = cdiv(M_ALL * 64, 256);    // 20000

    // ---- parameter prep ----
    lamP_kernel<<<16, 256, 0, stream>>>(a_log0, a_log1, B1, lam0, P1);
    bias_prep_kernel<<<2, 256, 0, stream>>>(b_sage0, b_sage1, b_mix0, b_res0, b_mix1, b_res1,
                                            bcat0, bcat1, bmt0, bmt1);
    // cat regions: [self | neigh], NTN_tot = 32
    pack_b_kernel<<<cdiv(4*16*64, 256), 256, 0, stream>>>(w_self0,  wcat0p, 128, 256, 32, 0, 0);
    pack_b_kernel<<<cdiv(4*16*64, 256), 256, 0, stream>>>(w_neigh0, wcat0p, 128, 256, 32, 16, 0);
    pack_b_kernel<<<cdiv(8*16*64, 256), 256, 0, stream>>>(w_self1,  wcat1p, 256, 256, 32, 0, 0);
    pack_b_kernel<<<cdiv(8*16*64, 256), 256, 0, stream>>>(w_neigh1, wcat1p, 256, 256, 32, 16, 0);
    // mix weights with residual appended along K (kt_off = 128)
    pack_b_kernel<<<cdiv(128*16*64, 256), 256, 0, stream>>>(w_mix0, wmix0p, 4096, 256, 16, 0, 0);
    pack_b_kernel<<<cdiv(4*16*64, 256),   256, 0, stream>>>(w_res0, wmix0p, 128,  256, 16, 0, 128);
    pack_b_kernel<<<cdiv(128*16*64, 256), 256, 0, stream>>>(w_mix1, wmix1p, 4096, 256, 16, 0, 0);
    pack_b_kernel<<<cdiv(8*16*64, 256),   256, 0, stream>>>(w_res1, wmix1p, 256,  256, 16, 0, 128);
    pack_b_kernel<<<cdiv(8*4*64, 256), 256, 0, stream>>>(w_out, woutp, 256, 64, 4, 0, 0);

    // ---- token mixer + CSR build ----
    token_mix_kernel<<<cdiv(T_DIM*V_DIM*128/4, 256), 256, 0, stream>>>(xs, w_pre, b_pre, x0b);
    hipMemsetAsync(deg_cnt, 0, (size_t)T_DIM * V_DIM * 4, stream);
    hipMemsetAsync(fill_cnt, 0, (size_t)T_DIM * V_DIM * 4, stream);
    deg_kernel<<<cdiv(T_DIM*E_DIM, 256), 256, 0, stream>>>(ei, deg_cnt);
    scan_kernel<<<T_DIM, 1024, 0, stream>>>(deg_cnt, rowptr);
    invdeg_kernel<<<cdiv(T_DIM*V_DIM, 256), 256, 0, stream>>>(deg_cnt, invdeg);
    fill_kernel<<<cdiv(T_DIM*E_DIM, 256), 256, 0, stream>>>(ei, rowptr, fill_cnt, srcs);

    // ================= layer 0 (batched over all t) =================
    gemm_cat2_kernel<4><<<dim3(2, gMall), 256, 0, stream>>>(x0b, wcat0p, bcat0, hA, hB, M_ALL);
    gather_pack_kernel<<<gGat, 256, 0, stream>>>(hB, srcs, rowptr, invdeg, hA, hpack);
    gemm_mix_rec_kernel<4><<<V_DIM / 16, 256, 0, stream>>>(
        hpack, wmix0p, x0b, lam0, B0, bmt0, x1b);

    // ================= layer 1 (batched over all t; mix only at t=7) =================
    gemm_cat2_kernel<8><<<dim3(2, gMall), 256, 0, stream>>>(x1b, wcat1p, bcat1, hA, hB, M_ALL);
    gather_pack_kernel<<<gGat, 256, 0, stream>>>(hB, srcs, rowptr, invdeg, hA, hpack);
    gemm_mix_cf5_kernel<1, 8><<<cdiv(V_DIM, 16), 256, 0, stream>>>(
        hpack, wmix1p, x1b + (size_t)(T_DIM - 1) * V_DIM * 256, P1, bmt1, out1_b);

    // ================= head =================
    gemm16_kernel<1, 4, false><<<cdiv(V_DIM,32), 512, 0, stream>>>(
        out1_b, woutp, b_out, (float*)d_out, V_DIM, 256);
}

// Round 4
// 982.899 us; speedup vs baseline: 1.7791x; 1.0525x over previous
//
#include <hip/hip_runtime.h>
#include <cstdint>
#include <cstddef>

#define T_DIM 8
#define V_DIM 10000
#define E_DIM 100000
#define M_ALL (T_DIM * V_DIM)

typedef __attribute__((ext_vector_type(8))) short short8;
typedef __attribute__((ext_vector_type(4))) float floatx4;

__device__ __forceinline__ unsigned int f2bf(float f) {
    union { float f; unsigned int u; } v; v.f = f;
    unsigned int u = v.u;
    u = u + 0x7FFFu + ((u >> 16) & 1u);   // RNE
    return u >> 16;
}
__device__ __forceinline__ float bf2f(unsigned int s) {
    union { unsigned int u; float f; } v; v.u = s << 16;
    return v.f;
}
__device__ __forceinline__ short8 relu8(short8 x) {
    const short8 z = {0,0,0,0,0,0,0,0};
    return __builtin_elementwise_max(x, z);   // v_pk_max_i16: bf16 relu on bit pattern
}
union PK { uint4 u; short8 s; };

// ---- pack fp32 weight [K,Nw] into MFMA B-fragment order inside a concat buffer
// frag index fo = (kt + kt_off) * NTN_tot + nt_off + nt
__global__ void pack_b_kernel(const float* __restrict__ w, unsigned short* __restrict__ out,
                              int K, int Nw, int NTN_tot, int nt_off, int kt_off) {
    int tid = blockIdx.x * blockDim.x + threadIdx.x;
    int total = (K >> 5) * (Nw >> 4) * 64;
    if (tid >= total) return;
    int lane = tid & 63;
    int f = tid >> 6;
    int ntn_w = Nw >> 4;
    int nt = f % ntn_w;
    int kt = f / ntn_w;
    int kbase = kt * 32 + ((lane >> 4) << 3);
    int n = nt * 16 + (lane & 15);
    unsigned int vals[8];
#pragma unroll
    for (int j = 0; j < 8; ++j)
        vals[j] = f2bf(w[(size_t)(kbase + j) * Nw + n]);
    uint4 pk;
    pk.x = vals[0] | (vals[1] << 16);
    pk.y = vals[2] | (vals[3] << 16);
    pk.z = vals[4] | (vals[5] << 16);
    pk.w = vals[6] | (vals[7] << 16);
    size_t fo = (size_t)(kt + kt_off) * NTN_tot + nt_off + nt;
    *(uint4*)(out + (fo * 64 + lane) * 8) = pk;
}

// ---- token mixer ----
__global__ void token_mix_kernel(const float* __restrict__ xs, const float* __restrict__ w_pre,
                                 const float* __restrict__ b_pre, unsigned short* __restrict__ ob) {
    const int S = V_DIM * 128;
    int tid = blockIdx.x * blockDim.x + threadIdx.x;
    if (tid >= T_DIM * S / 4) return;
    int e = tid * 4;
    int t = e / S;
    int c = e & 127;
    floatx4 xm = {0.f,0.f,0.f,0.f}, xp = {0.f,0.f,0.f,0.f};
    floatx4 x0 = *(const floatx4*)(xs + e);
    if (t > 0)          xm = *(const floatx4*)(xs + e - S);
    if (t < T_DIM - 1)  xp = *(const floatx4*)(xs + e + S);
    uint2 p; unsigned int b[4];
#pragma unroll
    for (int j = 0; j < 4; ++j) {
        int cc = c + j;
        float r = xm[j]*w_pre[cc*3+0] + x0[j]*w_pre[cc*3+1] + xp[j]*w_pre[cc*3+2] + b_pre[cc];
        b[j] = f2bf(r);
    }
    p.x = b[0] | (b[1] << 16);
    p.y = b[2] | (b[3] << 16);
    *(uint2*)(ob + e) = p;
}

// ---- lam[k] = exp(-exp(a[k])) for both layers ----
__global__ void lam_kernel(const float* __restrict__ a0, const float* __restrict__ a1,
                           float* __restrict__ lam0, float* __restrict__ lam1) {
    int i = blockIdx.x * blockDim.x + threadIdx.x;
    if (i >= 4096) return;
    lam0[i] = expf(-expf(a0[i]));
    lam1[i] = expf(-expf(a1[i]));
}

// ---- bias prep: bcat = [b_sage | 0] per layer; bmt = b_mix + b_res ----
__global__ void bias_prep_kernel(const float* __restrict__ bs0, const float* __restrict__ bs1,
                                 const float* __restrict__ bm0, const float* __restrict__ br0,
                                 const float* __restrict__ bm1, const float* __restrict__ br1,
                                 float* __restrict__ bcat0, float* __restrict__ bcat1,
                                 float* __restrict__ bmt0, float* __restrict__ bmt1) {
    int i = blockIdx.x * blockDim.x + threadIdx.x;
    if (i < 512) {
        bcat0[i] = (i < 256) ? bs0[i] : 0.f;
        bcat1[i] = (i < 256) ? bs1[i] : 0.f;
    }
    if (i < 256) {
        bmt0[i] = bm0[i] + br0[i];
        bmt1[i] = bm1[i] + br1[i];
    }
}

// ================= CSR build =================
__global__ void deg_kernel(const int* __restrict__ ei, int* __restrict__ deg_cnt) {
    int tid = blockIdx.x * blockDim.x + threadIdx.x;
    if (tid >= T_DIM * E_DIM) return;
    int t = tid / E_DIM;
    int e = tid - t * E_DIM;
    int dst = ei[(size_t)t * 2 * E_DIM + E_DIM + e];
    if ((unsigned)dst < V_DIM) atomicAdd(deg_cnt + t * V_DIM + dst, 1);
}

__global__ void invdeg_kernel(const int* __restrict__ deg_cnt, float* __restrict__ inv) {
    int tid = blockIdx.x * blockDim.x + threadIdx.x;
    if (tid >= T_DIM * V_DIM) return;
    inv[tid] = 1.0f / (float)max(deg_cnt[tid], 1);
}

__global__ __launch_bounds__(1024)
void scan_kernel(const int* __restrict__ deg_cnt, int* __restrict__ rowptr) {
    __shared__ int sums[1024];
    int t = blockIdx.x;
    const int* d = deg_cnt + t * V_DIM;
    int* rp = rowptr + t * (V_DIM + 1);
    int tid = threadIdx.x;
    int base = tid * 10;
    int loc[10]; int s = 0;
#pragma unroll
    for (int j = 0; j < 10; ++j) {
        int v = base + j;
        int x = (v < V_DIM) ? d[v] : 0;
        loc[j] = s; s += x;
    }
    sums[tid] = s;
    __syncthreads();
    for (int o = 1; o < 1024; o <<= 1) {
        int v = (tid >= o) ? sums[tid - o] : 0;
        __syncthreads();
        sums[tid] += v;
        __syncthreads();
    }
    int prev = (tid == 0) ? 0 : sums[tid - 1];
#pragma unroll
    for (int j = 0; j < 10; ++j) {
        int v = base + j;
        if (v < V_DIM) rp[v] = prev + loc[j];
    }
    if (tid == 1023) rp[V_DIM] = sums[1023];
}

__global__ void fill_kernel(const int* __restrict__ ei, const int* __restrict__ rowptr,
                            int* __restrict__ fill_cnt, int* __restrict__ srcs) {
    int tid = blockIdx.x * blockDim.x + threadIdx.x;
    if (tid >= T_DIM * E_DIM) return;
    int t = tid / E_DIM;
    int e = tid - t * E_DIM;
    const int* eit = ei + (size_t)t * 2 * E_DIM;
    int src = eit[e];
    int dst = eit[E_DIM + e];
    if ((unsigned)src >= V_DIM || (unsigned)dst >= V_DIM) return;
    int pos = rowptr[t * (V_DIM + 1) + dst] + atomicAdd(fill_cnt + t * V_DIM + dst, 1);
    srcs[(size_t)t * E_DIM + pos] = src;
}

// ---- batched gather + slot-pack over all t: h = hb + (sum xn[src])*invdeg -> hpack[v][c][t]
__global__ void gather_pack_kernel(const unsigned short* __restrict__ xn, const int* __restrict__ srcs,
                                   const int* __restrict__ rowptr, const float* __restrict__ invdeg,
                                   const unsigned short* __restrict__ hb,
                                   unsigned short* __restrict__ hpack) {
    int gw = (blockIdx.x * blockDim.x + threadIdx.x) >> 6;
    int lane = threadIdx.x & 63;
    if (gw >= T_DIM * V_DIM) return;
    int t = gw / V_DIM;
    int v = gw - t * V_DIM;
    const int* rp = rowptr + t * (V_DIM + 1);
    int beg = rp[v], end = rp[v + 1];
    const int* st = srcs + (size_t)t * E_DIM;
    const unsigned short* xnt = xn + (size_t)t * V_DIM * 256;
    float a0 = 0.f, a1 = 0.f, a2 = 0.f, a3 = 0.f;
    for (int i = beg; i < end; ++i) {
        int s = st[i];
        uint2 p = *(const uint2*)(xnt + (size_t)s * 256 + lane * 4);
        a0 += bf2f(p.x & 0xffffu);
        a1 += bf2f(p.x >> 16);
        a2 += bf2f(p.y & 0xffffu);
        a3 += bf2f(p.y >> 16);
    }
    float inv = invdeg[t * V_DIM + v];
    uint2 h = *(const uint2*)(hb + ((size_t)t * V_DIM + v) * 256 + lane * 4);
    a0 = a0 * inv + bf2f(h.x & 0xffffu);
    a1 = a1 * inv + bf2f(h.x >> 16);
    a2 = a2 * inv + bf2f(h.y & 0xffffu);
    a3 = a3 * inv + bf2f(h.y >> 16);
    unsigned short* op = hpack + (size_t)v * 2048 + (size_t)(lane * 4) * 8 + t;
    op[0]  = (unsigned short)f2bf(a0);
    op[8]  = (unsigned short)f2bf(a1);
    op[16] = (unsigned short)f2bf(a2);
    op[24] = (unsigned short)f2bf(a3);
}

// ---- batched cat GEMM over all t: x @ [w_self|w_neigh]; region 0 -> d_self, 1 -> d_xn
template<int KT>
__global__ __launch_bounds__(256, 4)
void gemm_cat2_kernel(const unsigned short* __restrict__ A, const unsigned short* __restrict__ Bp,
                      const float* __restrict__ bias, unsigned short* __restrict__ d_self,
                      unsigned short* __restrict__ d_xn, int M) {
    const int w = threadIdx.x >> 6, lane = threadIdx.x & 63;
    const int quad = lane >> 4, l16 = lane & 15;
    const int region = blockIdx.x;
    const int m0 = blockIdx.y * 64;
    constexpr int K = KT * 32;
    floatx4 acc[4][4];
#pragma unroll
    for (int a = 0; a < 4; ++a)
#pragma unroll
        for (int b = 0; b < 4; ++b) acc[a][b] = (floatx4){0.f,0.f,0.f,0.f};
    const unsigned short* arow[4];
#pragma unroll
    for (int mi = 0; mi < 4; ++mi) {
        int r = m0 + mi * 16 + l16;
        if (r > M - 1) r = M - 1;
        arow[mi] = A + (size_t)r * K + quad * 8;
    }
    const unsigned short* bptr = Bp + ((size_t)(region * 16 + w * 4) * 64 + lane) * 8;
#pragma unroll
    for (int kt = 0; kt < KT; ++kt) {
        short8 bfr[4];
#pragma unroll
        for (int i = 0; i < 4; ++i) bfr[i] = *(const short8*)(bptr + i * 512);
        short8 af[4];
#pragma unroll
        for (int mi = 0; mi < 4; ++mi) af[mi] = *(const short8*)(arow[mi]);
#pragma unroll
        for (int mi = 0; mi < 4; ++mi)
#pragma unroll
            for (int i = 0; i < 4; ++i)
                acc[mi][i] = __builtin_amdgcn_mfma_f32_16x16x32_bf16(af[mi], bfr[i], acc[mi][i], 0, 0, 0);
        bptr += 32 * 512;
#pragma unroll
        for (int mi = 0; mi < 4; ++mi) arow[mi] += 32;
    }
#pragma unroll
    for (int mi = 0; mi < 4; ++mi) {
        int rbase = m0 + mi * 16 + quad * 4;
#pragma unroll
        for (int i = 0; i < 4; ++i) {
            int lcol = w * 64 + i * 16 + l16;
            float b = bias[region * 256 + lcol];
#pragma unroll
            for (int rr = 0; rr < 4; ++rr) {
                int row = rbase + rr;
                if (row < M) {
                    float v = acc[mi][i][rr] + b;
                    size_t off = (size_t)row * 256 + lcol;
                    if (region == 0) d_self[off] = (unsigned short)f2bf(v);
                    else             d_xn[off]  = (unsigned short)f2bf(v);
                }
            }
        }
    }
}

// ---- recurrence SSM + mix GEMM + residual, double-buffered Afrag pipeline ----
// NT=8: all 8 t outputs (layer 0). NT=1: only t=7 output (layer 1).
// Block: 16 rows x 256 cols. 32 phases of 128 k (4 kt). Iteration ph:
//   compute states for phase ph+1 -> Afrag[(ph+1)&1]   (VALU + ds_write)
//   MFMA consume Afrag[ph&1]                           (ds_read + MFMA)
//   one barrier  -> VALU and MFMA pipes overlap within and across blocks.
template<int NT, int KRT>
__global__ __launch_bounds__(256, 2)
void gemm_mix_rec2_kernel(const unsigned short* __restrict__ hp,   // hpack [V][256][8]
                          const unsigned short* __restrict__ Bp,   // packed [w_mix ; w_res]
                          const unsigned short* __restrict__ Ares, // residual rows: NT=8 [T][V][KR], NT=1 [V][KR]
                          const float* __restrict__ lam,           // [4096]
                          const float* __restrict__ Bv,            // [4096]
                          const float* __restrict__ bias,          // [256] = b_mix + b_res
                          unsigned short* __restrict__ out) {      // NT=8 [T][V][256], NT=1 [V][256]
    constexpr int KR = KRT * 32;
    __shared__ __align__(16) unsigned short Afrag[2][4 * NT * 64 * 8];
    const int tid = threadIdx.x;
    const int w = tid >> 6, lane = tid & 63;
    const int quad = lane >> 4, l16 = lane & 15;
    const int m0 = blockIdx.x * 16;
    // phase-1 assignment: thread -> (row, octet); 16 rows x 16 octets = 128 k
    const int prow = tid & 15;
    const int oct  = tid >> 4;           // 0..15
    const int kt_w = oct >> 2, qo = oct & 3;
    const int vr = m0 + prow;

    floatx4 acc[NT][4];
#pragma unroll
    for (int t = 0; t < NT; ++t)
#pragma unroll
        for (int i = 0; i < 4; ++i) acc[t][i] = (floatx4){0.f,0.f,0.f,0.f};

    const unsigned short* bptr = Bp + ((size_t)(w * 4) * 64 + lane) * 8;

    auto compute = [&](int ph, int buf) {
        const int kg = ph * 128 + kt_w * 32 + qo * 8;
        const int ch = kg >> 4;
        PK h8; h8.u = *(const uint4*)(hp + (size_t)vr * 2048 + (size_t)ch * 8);
        floatx4 l0 = *(const floatx4*)(lam + kg);
        floatx4 l1 = *(const floatx4*)(lam + kg + 4);
        floatx4 b0 = *(const floatx4*)(Bv + kg);
        floatx4 b1 = *(const floatx4*)(Bv + kg + 4);
        float s0=0.f,s1=0.f,s2=0.f,s3=0.f,s4=0.f,s5=0.f,s6=0.f,s7=0.f;
        unsigned short* ap = Afrag[buf] + ((size_t)(kt_w * NT) * 64 + qo * 16 + prow) * 8;
#pragma unroll
        for (int t = 0; t < 8; ++t) {
            float hv = bf2f((unsigned int)(unsigned short)h8.s[t]);
            s0 = l0[0]*s0 + hv*b0[0];
            s1 = l0[1]*s1 + hv*b0[1];
            s2 = l0[2]*s2 + hv*b0[2];
            s3 = l0[3]*s3 + hv*b0[3];
            s4 = l1[0]*s4 + hv*b1[0];
            s5 = l1[1]*s5 + hv*b1[1];
            s6 = l1[2]*s6 + hv*b1[2];
            s7 = l1[3]*s7 + hv*b1[3];
            if (NT == 8 || t == 7) {
                PK cv;
                cv.u.x = f2bf(s0) | (f2bf(s1) << 16);
                cv.u.y = f2bf(s2) | (f2bf(s3) << 16);
                cv.u.z = f2bf(s4) | (f2bf(s5) << 16);
                cv.u.w = f2bf(s6) | (f2bf(s7) << 16);
                PK st; st.s = relu8(cv.s);
                *(uint4*)(ap + (size_t)((NT == 8) ? t : 0) * 512) = st.u;
            }
        }
    };
    auto consume = [&](int buf) {
#pragma unroll
        for (int kt = 0; kt < 4; ++kt) {
            short8 bfr[4];
#pragma unroll
            for (int i = 0; i < 4; ++i) bfr[i] = *(const short8*)(bptr + i * 512);
#pragma unroll
            for (int t = 0; t < NT; ++t) {
                short8 af = *(const short8*)(Afrag[buf] + (size_t)((kt * NT + t) * 64 + lane) * 8);
#pragma unroll
                for (int i = 0; i < 4; ++i)
                    acc[t][i] = __builtin_amdgcn_mfma_f32_16x16x32_bf16(af, bfr[i], acc[t][i], 0, 0, 0);
            }
            bptr += 16 * 512;
        }
    };

    compute(0, 0);
    __syncthreads();
    for (int ph = 0; ph < 32; ++ph) {
        if (ph < 31) compute(ph + 1, (ph + 1) & 1);
        consume(ph & 1);
        __syncthreads();
    }

    // ---- residual tail: acc[t] += x(t) @ w_res ----
#pragma unroll
    for (int ktr = 0; ktr < KRT; ++ktr) {
        short8 bfr[4];
#pragma unroll
        for (int i = 0; i < 4; ++i) bfr[i] = *(const short8*)(bptr + i * 512);
#pragma unroll
        for (int t = 0; t < NT; ++t) {
            const unsigned short* ar = Ares + ((size_t)t * V_DIM + (size_t)(m0 + l16)) * KR + ktr * 32 + quad * 8;
            short8 af = *(const short8*)ar;
#pragma unroll
            for (int i = 0; i < 4; ++i)
                acc[t][i] = __builtin_amdgcn_mfma_f32_16x16x32_bf16(af, bfr[i], acc[t][i], 0, 0, 0);
        }
        bptr += 16 * 512;
    }
    // ---- epilogue: bias + bf16 store, per t ----
#pragma unroll
    for (int t = 0; t < NT; ++t) {
#pragma unroll
        for (int i = 0; i < 4; ++i) {
            int col = w * 64 + i * 16 + l16;
            float b = bias[col];
#pragma unroll
            for (int rr = 0; rr < 4; ++rr) {
                int row = m0 + quad * 4 + rr;
                out[((size_t)t * V_DIM + row) * 256 + col] = (unsigned short)f2bf(acc[t][i][rr] + b);
            }
        }
    }
}

// ---- small GEMM (head): 32-row blocks, 8 waves ----
template<int NT, int NTN_TOT, bool RELU>
__global__ __launch_bounds__(512)
void gemm16_kernel(const unsigned short* __restrict__ A, const unsigned short* __restrict__ Bp,
                   const float* __restrict__ bias, float* __restrict__ outF, int M, int K) {
    const int w = threadIdx.x >> 6, lane = threadIdx.x & 63;
    const int quad = lane >> 4, l16 = lane & 15;
    const int rowgrp = w >> 2, nchunk = w & 3;
    const int m0 = blockIdx.x * 32 + rowgrp * 16;
    const int ntb = nchunk * NT;
    constexpr int Ntot = NTN_TOT * 16;
    floatx4 acc[NT];
#pragma unroll
    for (int i = 0; i < NT; ++i) acc[i] = (floatx4){0.f,0.f,0.f,0.f};
    int r = m0 + l16; if (r > M - 1) r = M - 1;
    const unsigned short* arow = A + (size_t)r * K + quad * 8;
    const int ksteps = K >> 5;
    for (int kt = 0; kt < ksteps; ++kt) {
        short8 af = *(const short8*)(arow + kt * 32);
        if (RELU) af = relu8(af);
#pragma unroll
        for (int i = 0; i < NT; ++i) {
            short8 bf = *(const short8*)(Bp + ((size_t)(kt * NTN_TOT + ntb + i) * 64 + lane) * 8);
            acc[i] = __builtin_amdgcn_mfma_f32_16x16x32_bf16(af, bf, acc[i], 0, 0, 0);
        }
    }
    const int rbase = m0 + quad * 4;
#pragma unroll
    for (int i = 0; i < NT; ++i) {
        int col = (ntb + i) * 16 + l16;
        float b = bias[col];
#pragma unroll
        for (int rr = 0; rr < 4; ++rr) {
            int row = rbase + rr;
            if (row < M)
                outF[(size_t)row * Ntot + col] = acc[i][rr] + b;
        }
    }
}

extern "C" void kernel_launch(void* const* d_in, const int* in_sizes, int n_in,
                              void* d_out, int out_size, void* d_ws, size_t ws_size,
                              hipStream_t stream) {
    const float* xs      = (const float*)d_in[0];
    const int*   ei      = (const int*)d_in[1];
    const float* w_pre   = (const float*)d_in[2];
    const float* b_pre   = (const float*)d_in[3];
    const float* w_res0  = (const float*)d_in[4];
    const float* b_res0  = (const float*)d_in[5];
    const float* w_self0 = (const float*)d_in[6];
    const float* w_neigh0= (const float*)d_in[7];
    const float* b_sage0 = (const float*)d_in[8];
    const float* a_log0  = (const float*)d_in[9];
    const float* B0      = (const float*)d_in[10];
    const float* w_mix0  = (const float*)d_in[11];
    const float* b_mix0  = (const float*)d_in[12];
    const float* w_res1  = (const float*)d_in[13];
    const float* b_res1  = (const float*)d_in[14];
    const float* w_self1 = (const float*)d_in[15];
    const float* w_neigh1= (const float*)d_in[16];
    const float* b_sage1 = (const float*)d_in[17];
    const float* a_log1  = (const float*)d_in[18];
    const float* B1      = (const float*)d_in[19];
    const float* w_mix1  = (const float*)d_in[20];
    const float* b_mix1  = (const float*)d_in[21];
    const float* w_out   = (const float*)d_in[22];
    const float* b_out   = (const float*)d_in[23];

    char* wsB = (char*)d_ws;
    size_t off = 0;
    auto alloc = [&](size_t bytes) {
        char* p = wsB + off;
        off += (bytes + 255) & ~(size_t)255;
        return p;
    };
    unsigned short* x0b   = (unsigned short*)alloc((size_t)M_ALL * 128 * 2);   // token-mixed input, all t
    unsigned short* hA    = (unsigned short*)alloc((size_t)M_ALL * 256 * 2);   // self part (both layers)
    unsigned short* hB    = (unsigned short*)alloc((size_t)M_ALL * 256 * 2);   // neigh part (both layers)
    unsigned short* hpack = (unsigned short*)alloc((size_t)V_DIM * 2048 * 2);  // [V][256][8] (both layers)
    unsigned short* x1b   = (unsigned short*)alloc((size_t)M_ALL * 256 * 2);   // layer-0 output, all t
    unsigned short* out1_b= (unsigned short*)alloc((size_t)V_DIM * 256 * 2);
    int*            deg_cnt = (int*)alloc((size_t)T_DIM * V_DIM * 4);
    float*          invdeg  = (float*)alloc((size_t)T_DIM * V_DIM * 4);
    int*            rowptr  = (int*)alloc((size_t)T_DIM * (V_DIM + 1) * 4);
    int*            fill_cnt= (int*)alloc((size_t)T_DIM * V_DIM * 4);
    int*            srcs    = (int*)alloc((size_t)T_DIM * E_DIM * 4);
    float*          lam0  = (float*)alloc(4096 * 4);
    float*          lam1  = (float*)alloc(4096 * 4);
    float*          bcat0 = (float*)alloc(512 * 4);
    float*          bcat1 = (float*)alloc(512 * 4);
    float*          bmt0  = (float*)alloc(256 * 4);
    float*          bmt1  = (float*)alloc(256 * 4);
    unsigned short* wcat0p= (unsigned short*)alloc((size_t)128 * 512 * 2);
    unsigned short* wcat1p= (unsigned short*)alloc((size_t)256 * 512 * 2);
    unsigned short* wmix0p= (unsigned short*)alloc((size_t)(4096 + 128) * 256 * 2);
    unsigned short* wmix1p= (unsigned short*)alloc((size_t)(4096 + 256) * 256 * 2);
    unsigned short* woutp = (unsigned short*)alloc((size_t)256 * 64 * 2);
    if (off > ws_size) return;   // fail cleanly, not a GPU fault

    auto cdiv = [](int a, int b) { return (a + b - 1) / b; };
    const int gMall = cdiv(M_ALL, 64);          // 1250
    const int gGat  = cdiv(M_ALL * 64, 256);    // 20000

    // ---- parameter prep ----
    lam_kernel<<<16, 256, 0, stream>>>(a_log0, a_log1, lam0, lam1);
    bias_prep_kernel<<<2, 256, 0, stream>>>(b_sage0, b_sage1, b_mix0, b_res0, b_mix1, b_res1,
                                            bcat0, bcat1, bmt0, bmt1);
    // cat regions: [self | neigh], NTN_tot = 32
    pack_b_kernel<<<cdiv(4*16*64, 256), 256, 0, stream>>>(w_self0,  wcat0p, 128, 256, 32, 0, 0);
    pack_b_kernel<<<cdiv(4*16*64, 256), 256, 0, stream>>>(w_neigh0, wcat0p, 128, 256, 32, 16, 0);
    pack_b_kernel<<<cdiv(8*16*64, 256), 256, 0, stream>>>(w_self1,  wcat1p, 256, 256, 32, 0, 0);
    pack_b_kernel<<<cdiv(8*16*64, 256), 256, 0, stream>>>(w_neigh1, wcat1p, 256, 256, 32, 16, 0);
    // mix weights with residual appended along K (kt_off = 128)
    pack_b_kernel<<<cdiv(128*16*64, 256), 256, 0, stream>>>(w_mix0, wmix0p, 4096, 256, 16, 0, 0);
    pack_b_kernel<<<cdiv(4*16*64, 256),   256, 0, stream>>>(w_res0, wmix0p, 128,  256, 16, 0, 128);
    pack_b_kernel<<<cdiv(128*16*64, 256), 256, 0, stream>>>(w_mix1, wmix1p, 4096, 256, 16, 0, 0);
    pack_b_kernel<<<cdiv(8*16*64, 256),   256, 0, stream>>>(w_res1, wmix1p, 256,  256, 16, 0, 128);
    pack_b_kernel<<<cdiv(8*4*64, 256), 256, 0, stream>>>(w_out, woutp, 256, 64, 4, 0, 0);

    // ---- token mixer + CSR build ----
    token_mix_kernel<<<cdiv(T_DIM*V_DIM*128/4, 256), 256, 0, stream>>>(xs, w_pre, b_pre, x0b);
    hipMemsetAsync(deg_cnt, 0, (size_t)T_DIM * V_DIM * 4, stream);
    hipMemsetAsync(fill_cnt, 0, (size_t)T_DIM * V_DIM * 4, stream);
    deg_kernel<<<cdiv(T_DIM*E_DIM, 256), 256, 0, stream>>>(ei, deg_cnt);
    scan_kernel<<<T_DIM, 1024, 0, stream>>>(deg_cnt, rowptr);
    invdeg_kernel<<<cdiv(T_DIM*V_DIM, 256), 256, 0, stream>>>(deg_cnt, invdeg);
    fill_kernel<<<cdiv(T_DIM*E_DIM, 256), 256, 0, stream>>>(ei, rowptr, fill_cnt, srcs);

    // ================= layer 0 (batched over all t) =================
    gemm_cat2_kernel<4><<<dim3(2, gMall), 256, 0, stream>>>(x0b, wcat0p, bcat0, hA, hB, M_ALL);
    gather_pack_kernel<<<gGat, 256, 0, stream>>>(hB, srcs, rowptr, invdeg, hA, hpack);
    gemm_mix_rec2_kernel<8, 4><<<V_DIM / 16, 256, 0, stream>>>(
        hpack, wmix0p, x0b, lam0, B0, bmt0, x1b);

    // ================= layer 1 (batched over all t; mix only at t=7) =================
    gemm_cat2_kernel<8><<<dim3(2, gMall), 256, 0, stream>>>(x1b, wcat1p, bcat1, hA, hB, M_ALL);
    gather_pack_kernel<<<gGat, 256, 0, stream>>>(hB, srcs, rowptr, invdeg, hA, hpack);
    gemm_mix_rec2_kernel<1, 8><<<V_DIM / 16, 256, 0, stream>>>(
        hpack, wmix1p, x1b + (size_t)(T_DIM - 1) * V_DIM * 256, lam1, B1, bmt1, out1_b);

    // ================= head =================
    gemm16_kernel<1, 4, false><<<cdiv(V_DIM,32), 512, 0, stream>>>(
        out1_b, woutp, b_out, (float*)d_out, V_DIM, 256);
}